// Round 5
// baseline (5640.888 us; speedup 1.0000x reference)
//
#include <hip/hip_runtime.h>

#define B_ 4
#define S_ 2048
#define D_ 1024
#define H_ 16
#define DK_ 64
#define M_ (B_*S_)   // 8192 rows
#define K_ D_        // 1024
#define N_ D_        // 1024

typedef unsigned short u16;
typedef unsigned int u32;
typedef __bf16 bf16x8 __attribute__((ext_vector_type(8)));
typedef float f32x4 __attribute__((ext_vector_type(4)));

__device__ __forceinline__ u16 f2bf(float f) {
    u32 u = __builtin_bit_cast(u32, f);
    u += 0x7fff + ((u >> 16) & 1);   // round-to-nearest-even
    return (u16)(u >> 16);
}
__device__ __forceinline__ float bf2f(u16 h) {
    u32 u = ((u32)h) << 16;
    return __builtin_bit_cast(float, u);
}
// packed bf16 pair -> floats (lo = bits 0-15, hi = bits 16-31)
__device__ __forceinline__ float blo(u32 p) { return __builtin_bit_cast(float, p << 16); }
__device__ __forceinline__ float bhi(u32 p) { return __builtin_bit_cast(float, p & 0xffff0000u); }

// ---------------------------------------------------------------------------
// fp32 -> bf16 elementwise convert (inputs arrive as float32 per reference)
// ---------------------------------------------------------------------------
__global__ __launch_bounds__(256) void cvt_f32_bf16(const float* __restrict__ in,
                                                    u16* __restrict__ out, int n4) {
    const int i = blockIdx.x * 256 + threadIdx.x;
    if (i >= n4) return;
    const float4 f = *(const float4*)(in + (size_t)i * 4);
    u32 p0 = (u32)f2bf(f.x) | ((u32)f2bf(f.y) << 16);
    u32 p1 = (u32)f2bf(f.z) | ((u32)f2bf(f.w) << 16);
    *(uint2*)(out + (size_t)i * 4) = make_uint2(p0, p1);
}

// ---------------------------------------------------------------------------
// GEMM: C[M_][N_] = A[M_][K_] * Bm[N_][K_]^T  (bf16 in, fp32 accum)
// 128x128 tile, BK=32, 4 waves 2x2, each wave 64x64 (4x4 MFMA frags).
// Plain staging (audited): thread t stages row t>>1, col half (t&1)*16.
// ---------------------------------------------------------------------------
template <bool F32OUT>
__device__ __forceinline__ void gemm_tile(const u16* __restrict__ A,
                                          const u16* __restrict__ Bm,
                                          void* __restrict__ Cv) {
    __shared__ u16 As[128 * 32];
    __shared__ u16 Bs[128 * 32];
    const int tid  = threadIdx.x;
    const int wave = tid >> 6, lane = tid & 63;
    const int m0 = blockIdx.y * 128, n0 = blockIdx.x * 128;
    const int wm = wave & 1, wn = wave >> 1;
    const int quad = lane >> 4, mcol = lane & 15;

    const int srow = tid >> 1;          // 0..127
    const int scol = (tid & 1) * 16;    // 0 or 16

    f32x4 acc[4][4];
#pragma unroll
    for (int i = 0; i < 4; i++)
#pragma unroll
        for (int j = 0; j < 4; j++) acc[i][j] = f32x4{0.f, 0.f, 0.f, 0.f};

    for (int kt = 0; kt < K_; kt += 32) {
        __syncthreads();
        const uint4 a0 = *(const uint4*)(A  + (size_t)(m0 + srow) * K_ + kt + scol);
        const uint4 a1 = *(const uint4*)(A  + (size_t)(m0 + srow) * K_ + kt + scol + 8);
        const uint4 b0 = *(const uint4*)(Bm + (size_t)(n0 + srow) * K_ + kt + scol);
        const uint4 b1 = *(const uint4*)(Bm + (size_t)(n0 + srow) * K_ + kt + scol + 8);
        *(uint4*)&As[srow * 32 + scol]     = a0;
        *(uint4*)&As[srow * 32 + scol + 8] = a1;
        *(uint4*)&Bs[srow * 32 + scol]     = b0;
        *(uint4*)&Bs[srow * 32 + scol + 8] = b1;
        __syncthreads();

        bf16x8 af[4], bfr[4];
#pragma unroll
        for (int i = 0; i < 4; i++) {
            af[i]  = *(const bf16x8*)&As[(size_t)(wm * 64 + i * 16 + mcol) * 32 + quad * 8];
            bfr[i] = *(const bf16x8*)&Bs[(size_t)(wn * 64 + i * 16 + mcol) * 32 + quad * 8];
        }
#pragma unroll
        for (int i = 0; i < 4; i++)
#pragma unroll
            for (int j = 0; j < 4; j++)
                acc[i][j] = __builtin_amdgcn_mfma_f32_16x16x32_bf16(
                    af[i], bfr[j], acc[i][j], 0, 0, 0);
    }

    // epilogue: C/D layout row=(lane>>4)*4+reg, col=lane&15
#pragma unroll
    for (int i = 0; i < 4; i++) {
        const int row = m0 + wm * 64 + i * 16 + quad * 4;
#pragma unroll
        for (int j = 0; j < 4; j++) {
            const int col = n0 + wn * 64 + j * 16 + mcol;
#pragma unroll
            for (int r = 0; r < 4; r++) {
                if constexpr (F32OUT)
                    ((float*)Cv)[(size_t)(row + r) * N_ + col] = acc[i][j][r];
                else
                    ((u16*)Cv)[(size_t)(row + r) * N_ + col] = f2bf(acc[i][j][r]);
            }
        }
    }
}

__global__ __launch_bounds__(256) void gemm_qkv_kernel(
    const u16* __restrict__ x,
    const u16* __restrict__ wq, const u16* __restrict__ wk, const u16* __restrict__ wv,
    u16* __restrict__ q, u16* __restrict__ k, u16* __restrict__ v) {
    const u16* Bm; u16* C;
    if (blockIdx.z == 0)      { Bm = wq; C = q; }
    else if (blockIdx.z == 1) { Bm = wk; C = k; }
    else                      { Bm = wv; C = v; }
    gemm_tile<false>(x, Bm, C);
}

__global__ __launch_bounds__(256) void gemm_out_kernel(
    const u16* __restrict__ o, const u16* __restrict__ wo, float* __restrict__ out) {
    gemm_tile<true>(o, wo, out);
}

// ---------------------------------------------------------------------------
// RoPE (interleaved) in-place on bf16 q and k. One thread = one pair.
// idx bits: i[0:5) h[5:9) s[9:20) b[20:22)
// ---------------------------------------------------------------------------
__global__ __launch_bounds__(256) void rope_qk(u16* __restrict__ q,
                                               u16* __restrict__ k,
                                               const int* __restrict__ pos) {
    const int idx = blockIdx.x * 256 + threadIdx.x;
    const int i = idx & 31;
    const int h = (idx >> 5) & (H_ - 1);
    const int s = (idx >> 9) & (S_ - 1);
    const int b = idx >> 20;
    const float p = (float)pos[s];
    const float inv = powf(10000.f, -(float)i / 32.f);
    const float ang = p * inv;
    float sn, cs;
    sincosf(ang, &sn, &cs);
    const size_t off = ((size_t)(b * S_ + s)) * D_ + h * DK_ + 2 * i;
    {
        float x1 = bf2f(q[off]), x2 = bf2f(q[off + 1]);
        q[off]     = f2bf(x1 * cs - x2 * sn);
        q[off + 1] = f2bf(x1 * sn + x2 * cs);
    }
    {
        float x1 = bf2f(k[off]), x2 = bf2f(k[off + 1]);
        k[off]     = f2bf(x1 * cs - x2 * sn);
        k[off + 1] = f2bf(x1 * sn + x2 * cs);
    }
}

// ---------------------------------------------------------------------------
// Causal flash attention, VALU-only (correctness baseline).
// Block = 64 q rows per (qt,h,b). Thread (qr=tid>>2, kq=tid&3).
// ---------------------------------------------------------------------------
__global__ __launch_bounds__(256) void attn_kernel(
    const u16* __restrict__ q, const u16* __restrict__ k,
    const u16* __restrict__ v, u16* __restrict__ o) {
    __shared__ u16 Qs[64][72];
    __shared__ u16 Ks[64][72];
    __shared__ u16 Vs[64][72];   // [key][d] row-major

    const int tid = threadIdx.x;
    const int qt = blockIdx.x, h = blockIdx.y, b = blockIdx.z;
    const int q0 = qt * 64;
    const int rr = tid >> 3, ch = tid & 7;   // staging: rows rr, rr+32; chunk ch

    *(uint4*)&Qs[rr][ch * 8] =
        *(const uint4*)(q + ((size_t)(b * S_ + q0 + rr)) * D_ + h * DK_ + ch * 8);
    *(uint4*)&Qs[rr + 32][ch * 8] =
        *(const uint4*)(q + ((size_t)(b * S_ + q0 + rr + 32)) * D_ + h * DK_ + ch * 8);
    __syncthreads();

    const int qr = tid >> 2;     // q row [0,64)
    const int kq = tid & 3;      // key quarter

    u32 qp[32];
#pragma unroll
    for (int w = 0; w < 32; w++) qp[w] = *(const u32*)&Qs[qr][w * 2];

    float m = -1e30f, l = 0.f;
    float O[64];
#pragma unroll
    for (int d = 0; d < 64; d++) O[d] = 0.f;

    for (int j = 0; j <= qt; j++) {
        __syncthreads();
        *(uint4*)&Ks[rr][ch * 8] =
            *(const uint4*)(k + ((size_t)(b * S_ + j * 64 + rr)) * D_ + h * DK_ + ch * 8);
        *(uint4*)&Ks[rr + 32][ch * 8] =
            *(const uint4*)(k + ((size_t)(b * S_ + j * 64 + rr + 32)) * D_ + h * DK_ + ch * 8);
        *(uint4*)&Vs[rr][ch * 8] =
            *(const uint4*)(v + ((size_t)(b * S_ + j * 64 + rr)) * D_ + h * DK_ + ch * 8);
        *(uint4*)&Vs[rr + 32][ch * 8] =
            *(const uint4*)(v + ((size_t)(b * S_ + j * 64 + rr + 32)) * D_ + h * DK_ + ch * 8);
        __syncthreads();

        float s[16];
#pragma unroll
        for (int kk = 0; kk < 16; kk++) {
            const u16* krow = &Ks[kq * 16 + kk][0];
            float acc = 0.f;
#pragma unroll
            for (int w = 0; w < 32; w++) {
                const u32 kp = *(const u32*)(krow + w * 2);
                acc += blo(qp[w]) * blo(kp) + bhi(qp[w]) * bhi(kp);
            }
            s[kk] = acc;
        }

#pragma unroll
        for (int kk = 0; kk < 16; kk++) {
            float sv = s[kk] * 0.125f;
            if (j * 64 + kq * 16 + kk > q0 + qr) sv = -1e30f;
            s[kk] = sv;
        }

        float mx = s[0];
#pragma unroll
        for (int kk = 1; kk < 16; kk++) mx = fmaxf(mx, s[kk]);
        mx = fmaxf(mx, __shfl_xor(mx, 1));
        mx = fmaxf(mx, __shfl_xor(mx, 2));
        const float mnew = fmaxf(m, mx);
        const float alpha = __expf(m - mnew);
        float lsum = 0.f;
#pragma unroll
        for (int kk = 0; kk < 16; kk++) {
            const float p = __expf(s[kk] - mnew);
            s[kk] = p;
            lsum += p;
        }
        lsum += __shfl_xor(lsum, 1);
        lsum += __shfl_xor(lsum, 2);
        l = l * alpha + lsum;
        m = mnew;

#pragma unroll
        for (int d = 0; d < 64; d++) O[d] *= alpha;
#pragma unroll
        for (int kk = 0; kk < 16; kk++) {
            const float p = s[kk];
            const u16* vrow = &Vs[kq * 16 + kk][0];
#pragma unroll
            for (int w = 0; w < 32; w++) {
                const u32 vp = *(const u32*)(vrow + w * 2);
                O[2 * w]     += p * blo(vp);
                O[2 * w + 1] += p * bhi(vp);
            }
        }
    }

#pragma unroll
    for (int d = 0; d < 64; d++) {
        O[d] += __shfl_xor(O[d], 1);
        O[d] += __shfl_xor(O[d], 2);
    }
    const float inv = 1.f / l;
    u32 packed[8];
#pragma unroll
    for (int t = 0; t < 8; t++) {
        const u16 lo16 = f2bf(O[kq * 16 + 2 * t] * inv);
        const u16 hi16 = f2bf(O[kq * 16 + 2 * t + 1] * inv);
        packed[t] = (u32)lo16 | ((u32)hi16 << 16);
    }
    u16* op = o + ((size_t)(b * S_ + q0 + qr)) * D_ + h * DK_ + kq * 16;
    *(uint4*)(op)     = *(uint4*)&packed[0];
    *(uint4*)(op + 8) = *(uint4*)&packed[4];
}

// ---------------------------------------------------------------------------
extern "C" void kernel_launch(void* const* d_in, const int* in_sizes, int n_in,
                              void* d_out, int out_size, void* d_ws, size_t ws_size,
                              hipStream_t stream) {
    // Inputs are float32 per the reference (jnp.float32 everywhere)
    const float* x  = (const float*)d_in[0];
    const float* wq = (const float*)d_in[1];
    const float* wk = (const float*)d_in[2];
    const float* wv = (const float*)d_in[3];
    const float* wo = (const float*)d_in[4];
    const int*   tp = (const int*)d_in[5];
    float* out = (float*)d_out;   // reference output dtype: float32

    u16* ws = (u16*)d_ws;
    const size_t NE = (size_t)M_ * D_;       // 8.4M elems
    const size_t WE = (size_t)N_ * K_;       // 1M elems
    u16* xb  = ws;                 // bf16 x
    u16* wqb = ws + NE;
    u16* wkb = wqb + WE;
    u16* wvb = wkb + WE;
    u16* wob = wvb + WE;
    u16* qb  = wob + WE;           // roped Q
    u16* kb  = qb + NE;            // roped K
    u16* vb  = (u16*)d_out;        // V parked in d_out (dead until final GEMM)
    u16* ob  = xb;                 // attention out aliases dead xb

    dim3 blk(256);
    cvt_f32_bf16<<<dim3((int)(NE / 1024)), blk, 0, stream>>>(x, xb, (int)(NE / 4));
    cvt_f32_bf16<<<dim3((int)(WE / 1024)), blk, 0, stream>>>(wq, wqb, (int)(WE / 4));
    cvt_f32_bf16<<<dim3((int)(WE / 1024)), blk, 0, stream>>>(wk, wkb, (int)(WE / 4));
    cvt_f32_bf16<<<dim3((int)(WE / 1024)), blk, 0, stream>>>(wv, wvb, (int)(WE / 4));
    cvt_f32_bf16<<<dim3((int)(WE / 1024)), blk, 0, stream>>>(wo, wob, (int)(WE / 4));

    gemm_qkv_kernel<<<dim3(N_ / 128, M_ / 128, 3), blk, 0, stream>>>(xb, wqb, wkb, wvb, qb, kb, vb);
    rope_qk<<<dim3((B_ * S_ * H_ * 32) / 256), blk, 0, stream>>>(qb, kb, tp);
    attn_kernel<<<dim3(S_ / 64, H_, B_), blk, 0, stream>>>(qb, kb, vb, ob);
    gemm_out_kernel<<<dim3(N_ / 128, M_ / 128, 1), blk, 0, stream>>>(ob, wob, out);
}

// Round 6
// 472.648 us; speedup vs baseline: 11.9347x; 11.9347x over previous
//
#include <hip/hip_runtime.h>

#define B_ 4
#define S_ 2048
#define D_ 1024
#define H_ 16
#define DK_ 64
#define M_ (B_*S_)   // 8192 rows
#define K_ D_        // 1024
#define N_ D_        // 1024

typedef unsigned short u16;
typedef unsigned int u32;
typedef __bf16 bf16x8 __attribute__((ext_vector_type(8)));
typedef float f32x4 __attribute__((ext_vector_type(4)));

__device__ __forceinline__ u16 f2bf(float f) {
    u32 u = __builtin_bit_cast(u32, f);
    u += 0x7fff + ((u >> 16) & 1);   // round-to-nearest-even
    return (u16)(u >> 16);
}
__device__ __forceinline__ float bf2f(u16 h) {
    u32 u = ((u32)h) << 16;
    return __builtin_bit_cast(float, u);
}

// ---------------------------------------------------------------------------
// fp32 -> bf16 elementwise convert (inputs are float32 per reference)
// ---------------------------------------------------------------------------
__global__ __launch_bounds__(256) void cvt_f32_bf16(const float* __restrict__ in,
                                                    u16* __restrict__ out, int n4) {
    const int i = blockIdx.x * 256 + threadIdx.x;
    if (i >= n4) return;
    const float4 f = *(const float4*)(in + (size_t)i * 4);
    u32 p0 = (u32)f2bf(f.x) | ((u32)f2bf(f.y) << 16);
    u32 p1 = (u32)f2bf(f.z) | ((u32)f2bf(f.w) << 16);
    *(uint2*)(out + (size_t)i * 4) = make_uint2(p0, p1);
}

// ---------------------------------------------------------------------------
// GEMM: C[M_][N_] = A[M_][K_] * Bm[N_][K_]^T  (bf16 in, fp32 accum)
// 128x128 tile, BK=32, 4 waves 2x2, each wave 64x64 (4x4 MFMA frags).
// Plain staging (validated round 5).
// ---------------------------------------------------------------------------
template <bool F32OUT>
__device__ __forceinline__ void gemm_tile(const u16* __restrict__ A,
                                          const u16* __restrict__ Bm,
                                          void* __restrict__ Cv) {
    __shared__ u16 As[128 * 32];
    __shared__ u16 Bs[128 * 32];
    const int tid  = threadIdx.x;
    const int wave = tid >> 6, lane = tid & 63;
    const int m0 = blockIdx.y * 128, n0 = blockIdx.x * 128;
    const int wm = wave & 1, wn = wave >> 1;
    const int quad = lane >> 4, mcol = lane & 15;

    const int srow = tid >> 1;          // 0..127
    const int scol = (tid & 1) * 16;    // 0 or 16

    f32x4 acc[4][4];
#pragma unroll
    for (int i = 0; i < 4; i++)
#pragma unroll
        for (int j = 0; j < 4; j++) acc[i][j] = f32x4{0.f, 0.f, 0.f, 0.f};

    for (int kt = 0; kt < K_; kt += 32) {
        __syncthreads();
        const uint4 a0 = *(const uint4*)(A  + (size_t)(m0 + srow) * K_ + kt + scol);
        const uint4 a1 = *(const uint4*)(A  + (size_t)(m0 + srow) * K_ + kt + scol + 8);
        const uint4 b0 = *(const uint4*)(Bm + (size_t)(n0 + srow) * K_ + kt + scol);
        const uint4 b1 = *(const uint4*)(Bm + (size_t)(n0 + srow) * K_ + kt + scol + 8);
        *(uint4*)&As[srow * 32 + scol]     = a0;
        *(uint4*)&As[srow * 32 + scol + 8] = a1;
        *(uint4*)&Bs[srow * 32 + scol]     = b0;
        *(uint4*)&Bs[srow * 32 + scol + 8] = b1;
        __syncthreads();

        bf16x8 af[4], bfr[4];
#pragma unroll
        for (int i = 0; i < 4; i++) {
            af[i]  = *(const bf16x8*)&As[(size_t)(wm * 64 + i * 16 + mcol) * 32 + quad * 8];
            bfr[i] = *(const bf16x8*)&Bs[(size_t)(wn * 64 + i * 16 + mcol) * 32 + quad * 8];
        }
#pragma unroll
        for (int i = 0; i < 4; i++)
#pragma unroll
            for (int j = 0; j < 4; j++)
                acc[i][j] = __builtin_amdgcn_mfma_f32_16x16x32_bf16(
                    af[i], bfr[j], acc[i][j], 0, 0, 0);
    }

    // epilogue: C/D layout row=(lane>>4)*4+reg, col=lane&15
#pragma unroll
    for (int i = 0; i < 4; i++) {
        const int row = m0 + wm * 64 + i * 16 + quad * 4;
#pragma unroll
        for (int j = 0; j < 4; j++) {
            const int col = n0 + wn * 64 + j * 16 + mcol;
#pragma unroll
            for (int r = 0; r < 4; r++) {
                if constexpr (F32OUT)
                    ((float*)Cv)[(size_t)(row + r) * N_ + col] = acc[i][j][r];
                else
                    ((u16*)Cv)[(size_t)(row + r) * N_ + col] = f2bf(acc[i][j][r]);
            }
        }
    }
}

__global__ __launch_bounds__(256) void gemm_qkv_kernel(
    const u16* __restrict__ x,
    const u16* __restrict__ wq, const u16* __restrict__ wk, const u16* __restrict__ wv,
    u16* __restrict__ q, u16* __restrict__ k, u16* __restrict__ v) {
    const u16* Bm; u16* C;
    if (blockIdx.z == 0)      { Bm = wq; C = q; }
    else if (blockIdx.z == 1) { Bm = wk; C = k; }
    else                      { Bm = wv; C = v; }
    gemm_tile<false>(x, Bm, C);
}

__global__ __launch_bounds__(256) void gemm_out_kernel(
    const u16* __restrict__ o, const u16* __restrict__ wo, float* __restrict__ out) {
    gemm_tile<true>(o, wo, out);
}

// ---------------------------------------------------------------------------
// RoPE (interleaved) in-place on bf16 q and k. One thread = one pair.
// ---------------------------------------------------------------------------
__global__ __launch_bounds__(256) void rope_qk(u16* __restrict__ q,
                                               u16* __restrict__ k,
                                               const int* __restrict__ pos) {
    const int idx = blockIdx.x * 256 + threadIdx.x;
    const int i = idx & 31;
    const int h = (idx >> 5) & (H_ - 1);
    const int s = (idx >> 9) & (S_ - 1);
    const int b = idx >> 20;
    const float p = (float)pos[s];
    const float inv = powf(10000.f, -(float)i / 32.f);
    const float ang = p * inv;
    float sn, cs;
    sincosf(ang, &sn, &cs);
    const size_t off = ((size_t)(b * S_ + s)) * D_ + h * DK_ + 2 * i;
    {
        float x1 = bf2f(q[off]), x2 = bf2f(q[off + 1]);
        q[off]     = f2bf(x1 * cs - x2 * sn);
        q[off + 1] = f2bf(x1 * sn + x2 * cs);
    }
    {
        float x1 = bf2f(k[off]), x2 = bf2f(k[off + 1]);
        k[off]     = f2bf(x1 * cs - x2 * sn);
        k[off + 1] = f2bf(x1 * sn + x2 * cs);
    }
}

// ---------------------------------------------------------------------------
// Transpose V: v[b*S+s][h*64+d] -> vt[((b*H+h)*64+d)*S + s]  (64x64 LDS tiles)
// ---------------------------------------------------------------------------
__global__ __launch_bounds__(256) void transpose_v(const u16* __restrict__ v,
                                                   u16* __restrict__ vt) {
    __shared__ u16 t[64][72];
    const int tid = threadIdx.x;
    const int s0 = blockIdx.x * 64, h = blockIdx.y, b = blockIdx.z;
    const int rr = tid >> 3, ch = tid & 7;   // rr in [0,32), ch in [0,8)
    *(uint4*)&t[rr][ch * 8] =
        *(const uint4*)(v + ((size_t)(b * S_ + s0 + rr)) * D_ + h * DK_ + ch * 8);
    *(uint4*)&t[rr + 32][ch * 8] =
        *(const uint4*)(v + ((size_t)(b * S_ + s0 + rr + 32)) * D_ + h * DK_ + ch * 8);
    __syncthreads();
#pragma unroll
    for (int pass = 0; pass < 2; pass++) {
        const int d = rr + pass * 32;
        uint4 u;
        u16* tp = (u16*)&u;
#pragma unroll
        for (int j = 0; j < 8; j++) tp[j] = t[ch * 8 + j][d];
        *(uint4*)(vt + ((size_t)((b * H_ + h) * DK_ + d)) * S_ + s0 + ch * 8) = u;
    }
}

// ---------------------------------------------------------------------------
// Causal flash attention, MFMA. Block = 64 q rows (4 waves x 16), 64-key tiles.
// q,k: [b*S+s][h*64+d]; vt: [(b*H+h)*64+d][s]; o: [b*S+s][h*64+d]
// ---------------------------------------------------------------------------
__global__ __launch_bounds__(256) void attn_kernel(
    const u16* __restrict__ q, const u16* __restrict__ k,
    const u16* __restrict__ vt, u16* __restrict__ o) {
    __shared__ u16 Qs[64][72];
    __shared__ u16 Ks[64][72];
    __shared__ u16 Vs[64][72];        // [d][key]
    __shared__ u16 Ps[4][16][72];     // per-wave P tile [q][key]

    const int tid = threadIdx.x, wave = tid >> 6, lane = tid & 63;
    const int qt = blockIdx.x, h = blockIdx.y, b = blockIdx.z;
    const int q0 = qt * 64;
    const int quad = lane >> 4, mcol = lane & 15;
    const int rr = tid >> 3, ch = tid & 7;   // staging: rows rr, rr+32; chunk ch

    // stage Q tile (64 x 64)
    *(uint4*)&Qs[rr][ch * 8] =
        *(const uint4*)(q + ((size_t)(b * S_ + q0 + rr)) * D_ + h * DK_ + ch * 8);
    *(uint4*)&Qs[rr + 32][ch * 8] =
        *(const uint4*)(q + ((size_t)(b * S_ + q0 + rr + 32)) * D_ + h * DK_ + ch * 8);
    __syncthreads();
    bf16x8 qf0 = *(const bf16x8*)&Qs[wave * 16 + mcol][quad * 8];
    bf16x8 qf1 = *(const bf16x8*)&Qs[wave * 16 + mcol][32 + quad * 8];

    float mrow[4], lrow[4];
    f32x4 oacc[4];
#pragma unroll
    for (int r = 0; r < 4; r++) { mrow[r] = -1e30f; lrow[r] = 0.f; }
#pragma unroll
    for (int dn = 0; dn < 4; dn++) oacc[dn] = f32x4{0.f, 0.f, 0.f, 0.f};

    const int qloc = wave * 16 + quad * 4;   // + r = this lane's local q rows

    for (int j = 0; j <= qt; j++) {
        __syncthreads();   // protect Ks/Vs/Ps from previous iteration readers
        *(uint4*)&Ks[rr][ch * 8] =
            *(const uint4*)(k + ((size_t)(b * S_ + j * 64 + rr)) * D_ + h * DK_ + ch * 8);
        *(uint4*)&Ks[rr + 32][ch * 8] =
            *(const uint4*)(k + ((size_t)(b * S_ + j * 64 + rr + 32)) * D_ + h * DK_ + ch * 8);
        *(uint4*)&Vs[rr][ch * 8] =
            *(const uint4*)(vt + ((size_t)((b * H_ + h) * DK_ + rr)) * S_ + j * 64 + ch * 8);
        *(uint4*)&Vs[rr + 32][ch * 8] =
            *(const uint4*)(vt + ((size_t)((b * H_ + h) * DK_ + rr + 32)) * S_ + j * 64 + ch * 8);
        __syncthreads();

        // S = Q K^T  (16 q rows x 64 keys per wave)
        f32x4 sf[4];
#pragma unroll
        for (int n = 0; n < 4; n++) {
            bf16x8 kf0 = *(const bf16x8*)&Ks[n * 16 + mcol][quad * 8];
            bf16x8 kf1 = *(const bf16x8*)&Ks[n * 16 + mcol][32 + quad * 8];
            f32x4 z = f32x4{0.f, 0.f, 0.f, 0.f};
            z = __builtin_amdgcn_mfma_f32_16x16x32_bf16(qf0, kf0, z, 0, 0, 0);
            z = __builtin_amdgcn_mfma_f32_16x16x32_bf16(qf1, kf1, z, 0, 0, 0);
            sf[n] = z;
        }
        // scale + causal mask (diagonal tile only)
#pragma unroll
        for (int n = 0; n < 4; n++)
#pragma unroll
            for (int r = 0; r < 4; r++) {
                float sv = sf[n][r] * 0.125f;
                if (j == qt && (n * 16 + mcol) > (qloc + r)) sv = -1e30f;
                sf[n][r] = sv;
            }
        // online softmax (rows live across the 16 mcol lanes of each quad)
        float alpha[4];
#pragma unroll
        for (int r = 0; r < 4; r++) {
            float mx = fmaxf(fmaxf(sf[0][r], sf[1][r]), fmaxf(sf[2][r], sf[3][r]));
            mx = fmaxf(mx, __shfl_xor(mx, 1));
            mx = fmaxf(mx, __shfl_xor(mx, 2));
            mx = fmaxf(mx, __shfl_xor(mx, 4));
            mx = fmaxf(mx, __shfl_xor(mx, 8));
            const float mnew = fmaxf(mrow[r], mx);
            alpha[r] = __expf(mrow[r] - mnew);
            float sum = 0.f;
#pragma unroll
            for (int n = 0; n < 4; n++) {
                float pv = __expf(sf[n][r] - mnew);
                sf[n][r] = pv;
                sum += pv;
            }
            sum += __shfl_xor(sum, 1);
            sum += __shfl_xor(sum, 2);
            sum += __shfl_xor(sum, 4);
            sum += __shfl_xor(sum, 8);
            lrow[r] = lrow[r] * alpha[r] + sum;
            mrow[r] = mnew;
        }
        // P -> LDS (bf16, per-wave region), rescale O
#pragma unroll
        for (int r = 0; r < 4; r++)
#pragma unroll
            for (int n = 0; n < 4; n++)
                Ps[wave][quad * 4 + r][n * 16 + mcol] = f2bf(sf[n][r]);
#pragma unroll
        for (int dn = 0; dn < 4; dn++)
#pragma unroll
            for (int r = 0; r < 4; r++) oacc[dn][r] *= alpha[r];
        __syncthreads();

        // O += P V
        bf16x8 pf0 = *(const bf16x8*)&Ps[wave][mcol][quad * 8];
        bf16x8 pf1 = *(const bf16x8*)&Ps[wave][mcol][32 + quad * 8];
#pragma unroll
        for (int dn = 0; dn < 4; dn++) {
            bf16x8 vf0 = *(const bf16x8*)&Vs[dn * 16 + mcol][quad * 8];
            bf16x8 vf1 = *(const bf16x8*)&Vs[dn * 16 + mcol][32 + quad * 8];
            oacc[dn] = __builtin_amdgcn_mfma_f32_16x16x32_bf16(pf0, vf0, oacc[dn], 0, 0, 0);
            oacc[dn] = __builtin_amdgcn_mfma_f32_16x16x32_bf16(pf1, vf1, oacc[dn], 0, 0, 0);
        }
    }

    // normalize + write O
#pragma unroll
    for (int dn = 0; dn < 4; dn++)
#pragma unroll
        for (int r = 0; r < 4; r++) {
            const int row = q0 + wave * 16 + quad * 4 + r;
            o[((size_t)(b * S_ + row)) * D_ + h * DK_ + dn * 16 + mcol] =
                f2bf(oacc[dn][r] / lrow[r]);
        }
}

// ---------------------------------------------------------------------------
extern "C" void kernel_launch(void* const* d_in, const int* in_sizes, int n_in,
                              void* d_out, int out_size, void* d_ws, size_t ws_size,
                              hipStream_t stream) {
    const float* x  = (const float*)d_in[0];
    const float* wq = (const float*)d_in[1];
    const float* wk = (const float*)d_in[2];
    const float* wv = (const float*)d_in[3];
    const float* wo = (const float*)d_in[4];
    const int*   tp = (const int*)d_in[5];
    float* out = (float*)d_out;   // fp32 output

    u16* ws = (u16*)d_ws;
    const size_t NE = (size_t)M_ * D_;       // 8.4M elems
    const size_t WE = (size_t)N_ * K_;       // 1M elems
    u16* xb  = ws;                 // bf16 x
    u16* wqb = ws + NE;
    u16* wkb = wqb + WE;
    u16* wvb = wkb + WE;
    u16* wob = wvb + WE;
    u16* qb  = wob + WE;           // roped Q
    u16* kb  = qb + NE;            // roped K
    // d_out is fp32 (2 bytes/elem * 2): park both bf16 V buffers there.
    u16* vb  = (u16*)d_out;        // V row-major  (dead after transpose)
    u16* vtb = (u16*)d_out + NE;   // V transposed [d][s] (dead before final GEMM)
    u16* ob  = xb;                 // attention out aliases dead xb

    dim3 blk(256);
    cvt_f32_bf16<<<dim3((int)(NE / 1024)), blk, 0, stream>>>(x, xb, (int)(NE / 4));
    cvt_f32_bf16<<<dim3((int)(WE / 1024)), blk, 0, stream>>>(wq, wqb, (int)(WE / 4));
    cvt_f32_bf16<<<dim3((int)(WE / 1024)), blk, 0, stream>>>(wk, wkb, (int)(WE / 4));
    cvt_f32_bf16<<<dim3((int)(WE / 1024)), blk, 0, stream>>>(wv, wvb, (int)(WE / 4));
    cvt_f32_bf16<<<dim3((int)(WE / 1024)), blk, 0, stream>>>(wo, wob, (int)(WE / 4));

    gemm_qkv_kernel<<<dim3(N_ / 128, M_ / 128, 3), blk, 0, stream>>>(xb, wqb, wkb, wvb, qb, kb, vb);
    rope_qk<<<dim3((B_ * S_ * H_ * 32) / 256), blk, 0, stream>>>(qb, kb, tp);
    transpose_v<<<dim3(S_ / 64, H_, B_), blk, 0, stream>>>(vb, vtb);
    attn_kernel<<<dim3(S_ / 64, H_, B_), blk, 0, stream>>>(qb, kb, vtb, ob);
    gemm_out_kernel<<<dim3(N_ / 128, M_ / 128, 1), blk, 0, stream>>>(ob, wob, out);
}

// Round 7
// 389.835 us; speedup vs baseline: 14.4699x; 1.2124x over previous
//
#include <hip/hip_runtime.h>

#define B_ 4
#define S_ 2048
#define D_ 1024
#define H_ 16
#define DK_ 64
#define M_ (B_*S_)   // 8192 rows
#define K_ D_        // 1024
#define N_ D_        // 1024

typedef unsigned short u16;
typedef unsigned int u32;
typedef __bf16 bf16x8 __attribute__((ext_vector_type(8)));
typedef float f32x4 __attribute__((ext_vector_type(4)));

__device__ __forceinline__ u16 f2bf(float f) {
    u32 u = __builtin_bit_cast(u32, f);
    u += 0x7fff + ((u >> 16) & 1);   // round-to-nearest-even
    return (u16)(u >> 16);
}
__device__ __forceinline__ float bf2f(u16 h) {
    u32 u = ((u32)h) << 16;
    return __builtin_bit_cast(float, u);
}

// ---------------------------------------------------------------------------
// fp32 -> bf16 converts (inputs are float32 per reference)
// ---------------------------------------------------------------------------
__global__ __launch_bounds__(256) void cvt_x(const float* __restrict__ in,
                                             u16* __restrict__ out, int n4) {
    const int i = blockIdx.x * 256 + threadIdx.x;
    if (i >= n4) return;
    const float4 f = *(const float4*)(in + (size_t)i * 4);
    u32 p0 = (u32)f2bf(f.x) | ((u32)f2bf(f.y) << 16);
    u32 p1 = (u32)f2bf(f.z) | ((u32)f2bf(f.w) << 16);
    *(uint2*)(out + (size_t)i * 4) = make_uint2(p0, p1);
}

__global__ __launch_bounds__(256) void cvt_w4(
    const float* __restrict__ w0, const float* __restrict__ w1,
    const float* __restrict__ w2, const float* __restrict__ w3,
    u16* __restrict__ o0, u16* __restrict__ o1,
    u16* __restrict__ o2, u16* __restrict__ o3) {
    const int wi = blockIdx.y;
    const float* in = (wi == 0) ? w0 : (wi == 1) ? w1 : (wi == 2) ? w2 : w3;
    u16* out       = (wi == 0) ? o0 : (wi == 1) ? o1 : (wi == 2) ? o2 : o3;
    const int i = blockIdx.x * 256 + threadIdx.x;
    const float4 f = *(const float4*)(in + (size_t)i * 4);
    u32 p0 = (u32)f2bf(f.x) | ((u32)f2bf(f.y) << 16);
    u32 p1 = (u32)f2bf(f.z) | ((u32)f2bf(f.w) << 16);
    *(uint2*)(out + (size_t)i * 4) = make_uint2(p0, p1);
}

// ---------------------------------------------------------------------------
// GEMM: C[M_][N_] = A[M_][K_] * Bm[N_][K_]^T  (bf16 in, fp32 accum)
// 128x128 tile, BK=32, 4 waves 2x2. Register prefetch of next K-slab issued
// before the MFMA phase so the barrier's vmcnt drain overlaps compute.
// ---------------------------------------------------------------------------
template <bool F32OUT>
__device__ __forceinline__ void gemm_tile(const u16* __restrict__ A,
                                          const u16* __restrict__ Bm,
                                          void* __restrict__ Cv) {
    __shared__ u16 As[128 * 32];
    __shared__ u16 Bs[128 * 32];
    const int tid  = threadIdx.x;
    const int wave = tid >> 6, lane = tid & 63;
    const int m0 = blockIdx.y * 128, n0 = blockIdx.x * 128;
    const int wm = wave & 1, wn = wave >> 1;
    const int quad = lane >> 4, mcol = lane & 15;

    const int srow = tid >> 1;          // 0..127
    const int scol = (tid & 1) * 16;    // 0 or 16

    const u16* arow = A  + (size_t)(m0 + srow) * K_ + scol;
    const u16* brow = Bm + (size_t)(n0 + srow) * K_ + scol;

    f32x4 acc[4][4];
#pragma unroll
    for (int i = 0; i < 4; i++)
#pragma unroll
        for (int j = 0; j < 4; j++) acc[i][j] = f32x4{0.f, 0.f, 0.f, 0.f};

    uint4 a0 = *(const uint4*)(arow);
    uint4 a1 = *(const uint4*)(arow + 8);
    uint4 b0 = *(const uint4*)(brow);
    uint4 b1 = *(const uint4*)(brow + 8);

    for (int kt = 0; kt < K_; kt += 32) {
        __syncthreads();   // protect LDS (also drains prefetch vmcnt)
        *(uint4*)&As[srow * 32 + scol]     = a0;
        *(uint4*)&As[srow * 32 + scol + 8] = a1;
        *(uint4*)&Bs[srow * 32 + scol]     = b0;
        *(uint4*)&Bs[srow * 32 + scol + 8] = b1;
        __syncthreads();   // staged data visible

        if (kt + 32 < K_) {   // prefetch next slab; overlaps MFMA below
            a0 = *(const uint4*)(arow + kt + 32);
            a1 = *(const uint4*)(arow + kt + 40);
            b0 = *(const uint4*)(brow + kt + 32);
            b1 = *(const uint4*)(brow + kt + 40);
        }

        bf16x8 af[4], bfr[4];
#pragma unroll
        for (int i = 0; i < 4; i++) {
            af[i]  = *(const bf16x8*)&As[(size_t)(wm * 64 + i * 16 + mcol) * 32 + quad * 8];
            bfr[i] = *(const bf16x8*)&Bs[(size_t)(wn * 64 + i * 16 + mcol) * 32 + quad * 8];
        }
#pragma unroll
        for (int i = 0; i < 4; i++)
#pragma unroll
            for (int j = 0; j < 4; j++)
                acc[i][j] = __builtin_amdgcn_mfma_f32_16x16x32_bf16(
                    af[i], bfr[j], acc[i][j], 0, 0, 0);
    }

    // epilogue: C/D layout row=(lane>>4)*4+reg, col=lane&15
#pragma unroll
    for (int i = 0; i < 4; i++) {
        const int row = m0 + wm * 64 + i * 16 + quad * 4;
#pragma unroll
        for (int j = 0; j < 4; j++) {
            const int col = n0 + wn * 64 + j * 16 + mcol;
#pragma unroll
            for (int r = 0; r < 4; r++) {
                if constexpr (F32OUT)
                    ((float*)Cv)[(size_t)(row + r) * N_ + col] = acc[i][j][r];
                else
                    ((u16*)Cv)[(size_t)(row + r) * N_ + col] = f2bf(acc[i][j][r]);
            }
        }
    }
}

__global__ __launch_bounds__(256) void gemm_qkv_kernel(
    const u16* __restrict__ x,
    const u16* __restrict__ wq, const u16* __restrict__ wk, const u16* __restrict__ wv,
    u16* __restrict__ q, u16* __restrict__ k, u16* __restrict__ v) {
    const u16* Bm; u16* C;
    if (blockIdx.z == 0)      { Bm = wq; C = q; }
    else if (blockIdx.z == 1) { Bm = wk; C = k; }
    else                      { Bm = wv; C = v; }
    gemm_tile<false>(x, Bm, C);
}

__global__ __launch_bounds__(256) void gemm_out_kernel(
    const u16* __restrict__ o, const u16* __restrict__ wo, float* __restrict__ out) {
    gemm_tile<true>(o, wo, out);
}

// ---------------------------------------------------------------------------
// RoPE (interleaved) in-place; Q additionally scaled by 1/8 (folds the
// 1/sqrt(DK) score scale into Q — rotation commutes with scaling).
// ---------------------------------------------------------------------------
__global__ __launch_bounds__(256) void rope_qk(u16* __restrict__ q,
                                               u16* __restrict__ k,
                                               const int* __restrict__ pos) {
    const int idx = blockIdx.x * 256 + threadIdx.x;
    const int i = idx & 31;
    const int h = (idx >> 5) & (H_ - 1);
    const int s = (idx >> 9) & (S_ - 1);
    const int b = idx >> 20;
    const float p = (float)pos[s];
    const float inv = powf(10000.f, -(float)i / 32.f);
    const float ang = p * inv;
    float sn, cs;
    sincosf(ang, &sn, &cs);
    const size_t off = ((size_t)(b * S_ + s)) * D_ + h * DK_ + 2 * i;
    {
        float x1 = bf2f(q[off]), x2 = bf2f(q[off + 1]);
        q[off]     = f2bf((x1 * cs - x2 * sn) * 0.125f);
        q[off + 1] = f2bf((x1 * sn + x2 * cs) * 0.125f);
    }
    {
        float x1 = bf2f(k[off]), x2 = bf2f(k[off + 1]);
        k[off]     = f2bf(x1 * cs - x2 * sn);
        k[off + 1] = f2bf(x1 * sn + x2 * cs);
    }
}

// ---------------------------------------------------------------------------
// Transpose V: v[b*S+s][h*64+d] -> vt[((b*H+h)*64+d)*S + s]
// ---------------------------------------------------------------------------
__global__ __launch_bounds__(256) void transpose_v(const u16* __restrict__ v,
                                                   u16* __restrict__ vt) {
    __shared__ u16 t[64][72];
    const int tid = threadIdx.x;
    const int s0 = blockIdx.x * 64, h = blockIdx.y, b = blockIdx.z;
    const int rr = tid >> 3, ch = tid & 7;
    *(uint4*)&t[rr][ch * 8] =
        *(const uint4*)(v + ((size_t)(b * S_ + s0 + rr)) * D_ + h * DK_ + ch * 8);
    *(uint4*)&t[rr + 32][ch * 8] =
        *(const uint4*)(v + ((size_t)(b * S_ + s0 + rr + 32)) * D_ + h * DK_ + ch * 8);
    __syncthreads();
#pragma unroll
    for (int pass = 0; pass < 2; pass++) {
        const int d = rr + pass * 32;
        uint4 u;
        u16* tp = (u16*)&u;
#pragma unroll
        for (int j = 0; j < 8; j++) tp[j] = t[ch * 8 + j][d];
        *(uint4*)(vt + ((size_t)((b * H_ + h) * DK_ + d)) * S_ + s0 + ch * 8) = u;
    }
}

// ---------------------------------------------------------------------------
// Causal flash attention, MFMA, S^T formulation.
// Block = 128 q rows (4 waves x 32), 64-key tiles. Q pre-scaled by 1/8.
// q,k: [b*S+s][h*64+d]; vt: [(b*H+h)*64+d][s]; o: [b*S+s][h*64+d]
// S^T = K·Q^T puts each q's 64 key-scores into one lane-column: softmax
// reduction = in-register + 2 shfls across quads. P written as packed b64
// into the wave's private region (aliases dead Q staging LDS); PV reads it
// back in A-operand layout (same-wave LDS, no barrier needed).
// ---------------------------------------------------------------------------
__global__ __launch_bounds__(256) void attn_kernel(
    const u16* __restrict__ q, const u16* __restrict__ k,
    const u16* __restrict__ vt, u16* __restrict__ o) {
    __shared__ u16 Qs[128][72];      // after init, wave w's rows [w*32, w*32+32) = P region
    __shared__ u16 Ks[64][72];       // [key][d]
    __shared__ u16 Vs[64][72];       // [d][key]

    const int tid = threadIdx.x, wave = tid >> 6, lane = tid & 63;
    const int qt = blockIdx.x, h = blockIdx.y, b = blockIdx.z;
    const int q0 = qt * 128;
    const int quad = lane >> 4, mcol = lane & 15;

    // stage Q tile (128 x 64): thread t -> row t>>1, 32-col half (t&1)*32
    {
        const int rr = tid >> 1, cc = (tid & 1) * 32;
        const u16* src = q + ((size_t)(b * S_ + q0 + rr)) * D_ + h * DK_ + cc;
        u16* dst = &Qs[rr][cc];
        *(uint4*)(dst)      = *(const uint4*)(src);
        *(uint4*)(dst + 8)  = *(const uint4*)(src + 8);
        *(uint4*)(dst + 16) = *(const uint4*)(src + 16);
        *(uint4*)(dst + 24) = *(const uint4*)(src + 24);
    }
    __syncthreads();
    // Q fragments (B-operand): lane holds Q[q=w*32+g*16+mcol][d=quad*8+j]
    bf16x8 qf[2][2];
#pragma unroll
    for (int g = 0; g < 2; g++) {
        qf[g][0] = *(const bf16x8*)&Qs[wave * 32 + g * 16 + mcol][quad * 8];
        qf[g][1] = *(const bf16x8*)&Qs[wave * 32 + g * 16 + mcol][32 + quad * 8];
    }
    u16* PsW = &Qs[wave * 32][0];   // this wave's private P region [32][72]

    float m[2] = {-1e30f, -1e30f}, l[2] = {0.f, 0.f};
    f32x4 oacc[2][4];
#pragma unroll
    for (int g = 0; g < 2; g++)
#pragma unroll
        for (int dn = 0; dn < 4; dn++) oacc[g][dn] = f32x4{0.f, 0.f, 0.f, 0.f};

    const int rr2 = tid >> 2, ch2 = (tid & 3) * 16;   // K/V staging coords
    const u16* krow = k + ((size_t)(b * S_ + rr2)) * D_ + h * DK_ + ch2;
    const u16* vrow = vt + ((size_t)((b * H_ + h) * DK_ + rr2)) * S_ + ch2;
    const int wq0 = q0 + wave * 32;    // this wave's lowest q row
    const int jmax = 2 * qt + 1;

    uint4 kr0 = *(const uint4*)(krow);
    uint4 kr1 = *(const uint4*)(krow + 8);
    uint4 vr0 = *(const uint4*)(vrow);
    uint4 vr1 = *(const uint4*)(vrow + 8);

    for (int j = 0; j <= jmax; j++) {
        __syncthreads();   // protect Ks/Vs (drains prev prefetch vmcnt too)
        *(uint4*)&Ks[rr2][ch2]     = kr0;
        *(uint4*)&Ks[rr2][ch2 + 8] = kr1;
        *(uint4*)&Vs[rr2][ch2]     = vr0;
        *(uint4*)&Vs[rr2][ch2 + 8] = vr1;
        __syncthreads();   // visible

        if (j < jmax) {    // prefetch next tile; in flight across compute
            kr0 = *(const uint4*)(krow + (size_t)(j + 1) * 64 * D_);
            kr1 = *(const uint4*)(krow + (size_t)(j + 1) * 64 * D_ + 8);
            vr0 = *(const uint4*)(vrow + (j + 1) * 64);
            vr1 = *(const uint4*)(vrow + (j + 1) * 64 + 8);
        }

        if (j * 64 > wq0 + 31) continue;   // tile fully masked for this wave

        // S^T = K·Q^T : st[g][n] holds D[key=j*64+n*16+quad*4+r][q=wq0+g*16+mcol]
        f32x4 st[2][4];
#pragma unroll
        for (int n = 0; n < 4; n++) {
            bf16x8 kf0 = *(const bf16x8*)&Ks[n * 16 + mcol][quad * 8];
            bf16x8 kf1 = *(const bf16x8*)&Ks[n * 16 + mcol][32 + quad * 8];
            f32x4 z0 = f32x4{0.f, 0.f, 0.f, 0.f};
            z0 = __builtin_amdgcn_mfma_f32_16x16x32_bf16(kf0, qf[0][0], z0, 0, 0, 0);
            z0 = __builtin_amdgcn_mfma_f32_16x16x32_bf16(kf1, qf[0][1], z0, 0, 0, 0);
            st[0][n] = z0;
            f32x4 z1 = f32x4{0.f, 0.f, 0.f, 0.f};
            z1 = __builtin_amdgcn_mfma_f32_16x16x32_bf16(kf0, qf[1][0], z1, 0, 0, 0);
            z1 = __builtin_amdgcn_mfma_f32_16x16x32_bf16(kf1, qf[1][1], z1, 0, 0, 0);
            st[1][n] = z1;
        }

        if (j * 64 + 63 > wq0) {   // causal mask needed somewhere in this tile
#pragma unroll
            for (int g = 0; g < 2; g++) {
                const int qg = wq0 + g * 16 + mcol;
#pragma unroll
                for (int n = 0; n < 4; n++)
#pragma unroll
                    for (int r = 0; r < 4; r++)
                        if (j * 64 + n * 16 + quad * 4 + r > qg) st[g][n][r] = -1e30f;
            }
        }

        // online softmax (per lane: one q column, 16 key values) + P pack
        float alphaT[2][4];
#pragma unroll
        for (int g = 0; g < 2; g++) {
            float mx = st[g][0][0];
#pragma unroll
            for (int n = 0; n < 4; n++)
#pragma unroll
                for (int r = 0; r < 4; r++) mx = fmaxf(mx, st[g][n][r]);
            mx = fmaxf(mx, __shfl_xor(mx, 16));
            mx = fmaxf(mx, __shfl_xor(mx, 32));
            const float mnew = fmaxf(m[g], mx);
            const float al = __expf(m[g] - mnew);
            float sum = 0.f;
#pragma unroll
            for (int n = 0; n < 4; n++)
#pragma unroll
                for (int r = 0; r < 4; r++) {
                    const float p = __expf(st[g][n][r] - mnew);
                    st[g][n][r] = p;
                    sum += p;
                }
            sum += __shfl_xor(sum, 16);
            sum += __shfl_xor(sum, 32);
            l[g] = l[g] * al + sum;
            m[g] = mnew;
#pragma unroll
            for (int r = 0; r < 4; r++) alphaT[g][r] = __shfl(al, quad * 4 + r);
            // P^T -> P region: lane writes keys n*16+quad*4..+3 of q=g*16+mcol
#pragma unroll
            for (int n = 0; n < 4; n++) {
                const u32 lo = (u32)f2bf(st[g][n][0]) | ((u32)f2bf(st[g][n][1]) << 16);
                const u32 hi = (u32)f2bf(st[g][n][2]) | ((u32)f2bf(st[g][n][3]) << 16);
                *(uint2*)&PsW[(g * 16 + mcol) * 72 + n * 16 + quad * 4] = make_uint2(lo, hi);
            }
        }

#pragma unroll
        for (int g = 0; g < 2; g++)
#pragma unroll
            for (int dn = 0; dn < 4; dn++)
#pragma unroll
                for (int r = 0; r < 4; r++) oacc[g][dn][r] *= alphaT[g][r];

        // O += P·V  (P from own-wave LDS region; no barrier needed)
        bf16x8 pf[2][2];
#pragma unroll
        for (int g = 0; g < 2; g++) {
            pf[g][0] = *(const bf16x8*)&PsW[(g * 16 + mcol) * 72 + quad * 8];
            pf[g][1] = *(const bf16x8*)&PsW[(g * 16 + mcol) * 72 + 32 + quad * 8];
        }
#pragma unroll
        for (int dn = 0; dn < 4; dn++) {
            bf16x8 vf0 = *(const bf16x8*)&Vs[dn * 16 + mcol][quad * 8];
            bf16x8 vf1 = *(const bf16x8*)&Vs[dn * 16 + mcol][32 + quad * 8];
#pragma unroll
            for (int g = 0; g < 2; g++) {
                oacc[g][dn] = __builtin_amdgcn_mfma_f32_16x16x32_bf16(pf[g][0], vf0, oacc[g][dn], 0, 0, 0);
                oacc[g][dn] = __builtin_amdgcn_mfma_f32_16x16x32_bf16(pf[g][1], vf1, oacc[g][dn], 0, 0, 0);
            }
        }
    }

    // normalize + write O (O rows are q = quad*4+r; l lives per mcol-q -> shfl)
#pragma unroll
    for (int g = 0; g < 2; g++) {
        float linv[4];
#pragma unroll
        for (int r = 0; r < 4; r++) linv[r] = 1.f / __shfl(l[g], quad * 4 + r);
#pragma unroll
        for (int dn = 0; dn < 4; dn++)
#pragma unroll
            for (int r = 0; r < 4; r++) {
                const int row = wq0 + g * 16 + quad * 4 + r;
                o[((size_t)(b * S_ + row)) * D_ + h * DK_ + dn * 16 + mcol] =
                    f2bf(oacc[g][dn][r] * linv[r]);
            }
    }
}

// ---------------------------------------------------------------------------
extern "C" void kernel_launch(void* const* d_in, const int* in_sizes, int n_in,
                              void* d_out, int out_size, void* d_ws, size_t ws_size,
                              hipStream_t stream) {
    const float* x  = (const float*)d_in[0];
    const float* wq = (const float*)d_in[1];
    const float* wk = (const float*)d_in[2];
    const float* wv = (const float*)d_in[3];
    const float* wo = (const float*)d_in[4];
    const int*   tp = (const int*)d_in[5];
    float* out = (float*)d_out;   // fp32 output

    u16* ws = (u16*)d_ws;
    const size_t NE = (size_t)M_ * D_;       // 8.4M elems
    const size_t WE = (size_t)N_ * K_;       // 1M elems
    u16* xb  = ws;                 // bf16 x
    u16* wqb = ws + NE;
    u16* wkb = wqb + WE;
    u16* wvb = wkb + WE;
    u16* wob = wvb + WE;
    u16* qb  = wob + WE;           // roped+scaled Q
    u16* kb  = qb + NE;            // roped K
    u16* vb  = (u16*)d_out;        // V row-major  (in fp32-sized d_out, dead after transpose)
    u16* vtb = (u16*)d_out + NE;   // V transposed [d][s] (dead before final GEMM)
    u16* ob  = xb;                 // attention out aliases dead xb

    dim3 blk(256);
    cvt_x<<<dim3((int)(NE / 1024)), blk, 0, stream>>>(x, xb, (int)(NE / 4));
    cvt_w4<<<dim3((int)(WE / 1024), 4), blk, 0, stream>>>(wq, wk, wv, wo, wqb, wkb, wvb, wob);

    gemm_qkv_kernel<<<dim3(N_ / 128, M_ / 128, 3), blk, 0, stream>>>(xb, wqb, wkb, wvb, qb, kb, vb);
    rope_qk<<<dim3((B_ * S_ * H_ * 32) / 256), blk, 0, stream>>>(qb, kb, tp);
    transpose_v<<<dim3(S_ / 64, H_, B_), blk, 0, stream>>>(vb, vtb);
    attn_kernel<<<dim3(S_ / 128, H_, B_), blk, 0, stream>>>(qb, kb, vtb, ob);
    gemm_out_kernel<<<dim3(N_ / 128, M_ / 128, 1), blk, 0, stream>>>(ob, wob, out);
}

// Round 8
// 325.786 us; speedup vs baseline: 17.3147x; 1.1966x over previous
//
#include <hip/hip_runtime.h>

#define B_ 4
#define S_ 2048
#define D_ 1024
#define H_ 16
#define DK_ 64
#define M_ (B_*S_)   // 8192 rows
#define K_ D_        // 1024
#define N_ D_        // 1024

typedef unsigned short u16;
typedef unsigned int u32;
typedef __bf16 bf16x8 __attribute__((ext_vector_type(8)));
typedef float f32x4 __attribute__((ext_vector_type(4)));

__device__ __forceinline__ u16 f2bf(float f) {
    u32 u = __builtin_bit_cast(u32, f);
    u += 0x7fff + ((u >> 16) & 1);   // round-to-nearest-even
    return (u16)(u >> 16);
}
__device__ __forceinline__ float bf2f(u16 h) {
    u32 u = ((u32)h) << 16;
    return __builtin_bit_cast(float, u);
}

#define GLDS16(g, l) __builtin_amdgcn_global_load_lds( \
    (__attribute__((address_space(1))) void*)(g),      \
    (__attribute__((address_space(3))) void*)(l), 16, 0, 0)

// ---------------------------------------------------------------------------
// fp32 -> bf16 converts (inputs are float32 per reference)
// ---------------------------------------------------------------------------
__global__ __launch_bounds__(256) void cvt_x(const float* __restrict__ in,
                                             u16* __restrict__ out, int n4) {
    const int i = blockIdx.x * 256 + threadIdx.x;
    if (i >= n4) return;
    const float4 f = *(const float4*)(in + (size_t)i * 4);
    u32 p0 = (u32)f2bf(f.x) | ((u32)f2bf(f.y) << 16);
    u32 p1 = (u32)f2bf(f.z) | ((u32)f2bf(f.w) << 16);
    *(uint2*)(out + (size_t)i * 4) = make_uint2(p0, p1);
}

__global__ __launch_bounds__(256) void cvt_w4(
    const float* __restrict__ w0, const float* __restrict__ w1,
    const float* __restrict__ w2, const float* __restrict__ w3,
    u16* __restrict__ o0, u16* __restrict__ o1,
    u16* __restrict__ o2, u16* __restrict__ o3) {
    const int wi = blockIdx.y;
    const float* in = (wi == 0) ? w0 : (wi == 1) ? w1 : (wi == 2) ? w2 : w3;
    u16* out       = (wi == 0) ? o0 : (wi == 1) ? o1 : (wi == 2) ? o2 : o3;
    const int i = blockIdx.x * 256 + threadIdx.x;
    const float4 f = *(const float4*)(in + (size_t)i * 4);
    u32 p0 = (u32)f2bf(f.x) | ((u32)f2bf(f.y) << 16);
    u32 p1 = (u32)f2bf(f.z) | ((u32)f2bf(f.w) << 16);
    *(uint2*)(out + (size_t)i * 4) = make_uint2(p0, p1);
}

// ---------------------------------------------------------------------------
// GEMM: C[M_][N_] = A[M_][K_] * Bm[N_][K_]^T  (bf16 in, fp32 accum)
// 128x128 tile, BK=32, 4 waves 2x2. Staging via global_load_lds width=16
// (m97 style): wave w stages chunks {w, w+4}; chunk c = rows 16c..16c+15 x 32 k.
// Lane i of a chunk: row 16c + i/4, k-cols (i&3)*8 -> LDS offset lane*16B.
// ---------------------------------------------------------------------------
template <bool F32OUT>
__device__ __forceinline__ void gemm_tile(const u16* __restrict__ A,
                                          const u16* __restrict__ Bm,
                                          void* __restrict__ Cv) {
    __shared__ u16 As[128 * 32];
    __shared__ u16 Bs[128 * 32];
    const int tid  = threadIdx.x;
    const int wave = tid >> 6, lane = tid & 63;
    const int m0 = blockIdx.y * 128, n0 = blockIdx.x * 128;
    const int wm = wave & 1, wn = wave >> 1;
    const int quad = lane >> 4, mcol = lane & 15;

    const int c0 = wave, c1 = wave + 4;
    const int r0 = c0 * 16 + (lane >> 2), r1 = c1 * 16 + (lane >> 2);
    const int kb = (lane & 3) * 8;
    const u16* ga0 = A  + (size_t)(m0 + r0) * K_ + kb;
    const u16* ga1 = A  + (size_t)(m0 + r1) * K_ + kb;
    const u16* gb0 = Bm + (size_t)(n0 + r0) * K_ + kb;
    const u16* gb1 = Bm + (size_t)(n0 + r1) * K_ + kb;
    u16* la0 = &As[c0 * 512];    // wave-uniform bases; HW adds lane*16B
    u16* la1 = &As[c1 * 512];
    u16* lb0 = &Bs[c0 * 512];
    u16* lb1 = &Bs[c1 * 512];

    f32x4 acc[4][4];
#pragma unroll
    for (int i = 0; i < 4; i++)
#pragma unroll
        for (int j = 0; j < 4; j++) acc[i][j] = f32x4{0.f, 0.f, 0.f, 0.f};

    for (int kt = 0; kt < K_; kt += 32) {
        __syncthreads();   // protect LDS from previous iteration's readers
        GLDS16(ga0, la0); GLDS16(ga1, la1);
        GLDS16(gb0, lb0); GLDS16(gb1, lb1);
        ga0 += 32; ga1 += 32; gb0 += 32; gb1 += 32;
        __syncthreads();   // drains vmcnt -> staged data visible

        bf16x8 af[4], bfr[4];
#pragma unroll
        for (int i = 0; i < 4; i++) {
            af[i]  = *(const bf16x8*)&As[(size_t)(wm * 64 + i * 16 + mcol) * 32 + quad * 8];
            bfr[i] = *(const bf16x8*)&Bs[(size_t)(wn * 64 + i * 16 + mcol) * 32 + quad * 8];
        }
#pragma unroll
        for (int i = 0; i < 4; i++)
#pragma unroll
            for (int j = 0; j < 4; j++)
                acc[i][j] = __builtin_amdgcn_mfma_f32_16x16x32_bf16(
                    af[i], bfr[j], acc[i][j], 0, 0, 0);
    }

    // epilogue: C/D layout row=(lane>>4)*4+reg, col=lane&15
#pragma unroll
    for (int i = 0; i < 4; i++) {
        const int row = m0 + wm * 64 + i * 16 + quad * 4;
#pragma unroll
        for (int j = 0; j < 4; j++) {
            const int col = n0 + wn * 64 + j * 16 + mcol;
#pragma unroll
            for (int r = 0; r < 4; r++) {
                if constexpr (F32OUT)
                    ((float*)Cv)[(size_t)(row + r) * N_ + col] = acc[i][j][r];
                else
                    ((u16*)Cv)[(size_t)(row + r) * N_ + col] = f2bf(acc[i][j][r]);
            }
        }
    }
}

__global__ __launch_bounds__(256) void gemm_qkv_kernel(
    const u16* __restrict__ x,
    const u16* __restrict__ wq, const u16* __restrict__ wk, const u16* __restrict__ wv,
    u16* __restrict__ q, u16* __restrict__ k, u16* __restrict__ v) {
    const u16* Bm; u16* C;
    if (blockIdx.z == 0)      { Bm = wq; C = q; }
    else if (blockIdx.z == 1) { Bm = wk; C = k; }
    else                      { Bm = wv; C = v; }
    gemm_tile<false>(x, Bm, C);
}

__global__ __launch_bounds__(256) void gemm_out_kernel(
    const u16* __restrict__ o, const u16* __restrict__ wo, float* __restrict__ out) {
    gemm_tile<true>(o, wo, out);
}

// ---------------------------------------------------------------------------
// RoPE (interleaved) in-place; Q additionally scaled by 1/8 (folds the
// 1/sqrt(DK) score scale into Q).
// ---------------------------------------------------------------------------
__global__ __launch_bounds__(256) void rope_qk(u16* __restrict__ q,
                                               u16* __restrict__ k,
                                               const int* __restrict__ pos) {
    const int idx = blockIdx.x * 256 + threadIdx.x;
    const int i = idx & 31;
    const int h = (idx >> 5) & (H_ - 1);
    const int s = (idx >> 9) & (S_ - 1);
    const int b = idx >> 20;
    const float p = (float)pos[s];
    const float inv = powf(10000.f, -(float)i / 32.f);
    const float ang = p * inv;
    float sn, cs;
    sincosf(ang, &sn, &cs);
    const size_t off = ((size_t)(b * S_ + s)) * D_ + h * DK_ + 2 * i;
    {
        float x1 = bf2f(q[off]), x2 = bf2f(q[off + 1]);
        q[off]     = f2bf((x1 * cs - x2 * sn) * 0.125f);
        q[off + 1] = f2bf((x1 * sn + x2 * cs) * 0.125f);
    }
    {
        float x1 = bf2f(k[off]), x2 = bf2f(k[off + 1]);
        k[off]     = f2bf(x1 * cs - x2 * sn);
        k[off + 1] = f2bf(x1 * sn + x2 * cs);
    }
}

// ---------------------------------------------------------------------------
// Transpose V: v[b*S+s][h*64+d] -> vt[((b*H+h)*64+d)*S + s]
// ---------------------------------------------------------------------------
__global__ __launch_bounds__(256) void transpose_v(const u16* __restrict__ v,
                                                   u16* __restrict__ vt) {
    __shared__ u16 t[64][72];
    const int tid = threadIdx.x;
    const int s0 = blockIdx.x * 64, h = blockIdx.y, b = blockIdx.z;
    const int rr = tid >> 3, ch = tid & 7;
    *(uint4*)&t[rr][ch * 8] =
        *(const uint4*)(v + ((size_t)(b * S_ + s0 + rr)) * D_ + h * DK_ + ch * 8);
    *(uint4*)&t[rr + 32][ch * 8] =
        *(const uint4*)(v + ((size_t)(b * S_ + s0 + rr + 32)) * D_ + h * DK_ + ch * 8);
    __syncthreads();
#pragma unroll
    for (int pass = 0; pass < 2; pass++) {
        const int d = rr + pass * 32;
        uint4 u;
        u16* tp = (u16*)&u;
#pragma unroll
        for (int j = 0; j < 8; j++) tp[j] = t[ch * 8 + j][d];
        *(uint4*)(vt + ((size_t)((b * H_ + h) * DK_ + d)) * S_ + s0 + ch * 8) = u;
    }
}

// ---------------------------------------------------------------------------
// Causal flash attention, MFMA, S^T formulation.
// Flat 1024-block grid, decoded qt = flat>>6 so that co-resident blocks on a
// CU (flat, flat+256, ...) get qt {a, a+4, a+8, a+12} -> per-CU causal work
// spread collapses from 16x to 1.5x (load balance; speed-only heuristic).
// Block = 128 q rows (4 waves x 32), 64-key tiles. Q pre-scaled by 1/8.
// ---------------------------------------------------------------------------
__global__ __launch_bounds__(256) void attn_kernel(
    const u16* __restrict__ q, const u16* __restrict__ k,
    const u16* __restrict__ vt, u16* __restrict__ o) {
    __shared__ u16 Qs[128][72];      // after init, wave w's rows [w*32,+32) = P region
    __shared__ u16 Ks[64][72];       // [key][d]
    __shared__ u16 Vs[64][72];       // [d][key]

    const int tid = threadIdx.x, wave = tid >> 6, lane = tid & 63;
    const int flat = blockIdx.x;
    const int qt = flat >> 6;
    const int h = flat & (H_ - 1);
    const int b = (flat >> 4) & 3;
    const int q0 = qt * 128;
    const int quad = lane >> 4, mcol = lane & 15;

    // stage Q tile (128 x 64): thread t -> row t>>1, 32-col half (t&1)*32
    {
        const int rr = tid >> 1, cc = (tid & 1) * 32;
        const u16* src = q + ((size_t)(b * S_ + q0 + rr)) * D_ + h * DK_ + cc;
        u16* dst = &Qs[rr][cc];
        *(uint4*)(dst)      = *(const uint4*)(src);
        *(uint4*)(dst + 8)  = *(const uint4*)(src + 8);
        *(uint4*)(dst + 16) = *(const uint4*)(src + 16);
        *(uint4*)(dst + 24) = *(const uint4*)(src + 24);
    }
    __syncthreads();
    // Q fragments (B-operand): lane holds Q[q=w*32+g*16+mcol][d=quad*8+j]
    bf16x8 qf[2][2];
#pragma unroll
    for (int g = 0; g < 2; g++) {
        qf[g][0] = *(const bf16x8*)&Qs[wave * 32 + g * 16 + mcol][quad * 8];
        qf[g][1] = *(const bf16x8*)&Qs[wave * 32 + g * 16 + mcol][32 + quad * 8];
    }
    u16* PsW = &Qs[wave * 32][0];   // this wave's private P region [32][72]

    float m[2] = {-1e30f, -1e30f}, l[2] = {0.f, 0.f};
    f32x4 oacc[2][4];
#pragma unroll
    for (int g = 0; g < 2; g++)
#pragma unroll
        for (int dn = 0; dn < 4; dn++) oacc[g][dn] = f32x4{0.f, 0.f, 0.f, 0.f};

    const int rr2 = tid >> 2, ch2 = (tid & 3) * 16;   // K/V staging coords
    const u16* krow = k + ((size_t)(b * S_ + rr2)) * D_ + h * DK_ + ch2;
    const u16* vrow = vt + ((size_t)((b * H_ + h) * DK_ + rr2)) * S_ + ch2;
    const int wq0 = q0 + wave * 32;    // this wave's lowest q row
    const int jmax = 2 * qt + 1;

    uint4 kr0 = *(const uint4*)(krow);
    uint4 kr1 = *(const uint4*)(krow + 8);
    uint4 vr0 = *(const uint4*)(vrow);
    uint4 vr1 = *(const uint4*)(vrow + 8);

    for (int j = 0; j <= jmax; j++) {
        __syncthreads();   // protect Ks/Vs (drains prev prefetch vmcnt too)
        *(uint4*)&Ks[rr2][ch2]     = kr0;
        *(uint4*)&Ks[rr2][ch2 + 8] = kr1;
        *(uint4*)&Vs[rr2][ch2]     = vr0;
        *(uint4*)&Vs[rr2][ch2 + 8] = vr1;
        __syncthreads();   // visible

        if (j < jmax) {    // prefetch next tile; in flight across compute
            kr0 = *(const uint4*)(krow + (size_t)(j + 1) * 64 * D_);
            kr1 = *(const uint4*)(krow + (size_t)(j + 1) * 64 * D_ + 8);
            vr0 = *(const uint4*)(vrow + (j + 1) * 64);
            vr1 = *(const uint4*)(vrow + (j + 1) * 64 + 8);
        }

        if (j * 64 > wq0 + 31) continue;   // tile fully masked for this wave

        // S^T = K·Q^T : st[g][n] = D[key=j*64+n*16+quad*4+r][q=wq0+g*16+mcol]
        f32x4 st[2][4];
#pragma unroll
        for (int n = 0; n < 4; n++) {
            bf16x8 kf0 = *(const bf16x8*)&Ks[n * 16 + mcol][quad * 8];
            bf16x8 kf1 = *(const bf16x8*)&Ks[n * 16 + mcol][32 + quad * 8];
            f32x4 z0 = f32x4{0.f, 0.f, 0.f, 0.f};
            z0 = __builtin_amdgcn_mfma_f32_16x16x32_bf16(kf0, qf[0][0], z0, 0, 0, 0);
            z0 = __builtin_amdgcn_mfma_f32_16x16x32_bf16(kf1, qf[0][1], z0, 0, 0, 0);
            st[0][n] = z0;
            f32x4 z1 = f32x4{0.f, 0.f, 0.f, 0.f};
            z1 = __builtin_amdgcn_mfma_f32_16x16x32_bf16(kf0, qf[1][0], z1, 0, 0, 0);
            z1 = __builtin_amdgcn_mfma_f32_16x16x32_bf16(kf1, qf[1][1], z1, 0, 0, 0);
            st[1][n] = z1;
        }

        if (j * 64 + 63 > wq0) {   // causal mask needed somewhere in this tile
#pragma unroll
            for (int g = 0; g < 2; g++) {
                const int qg = wq0 + g * 16 + mcol;
#pragma unroll
                for (int n = 0; n < 4; n++)
#pragma unroll
                    for (int r = 0; r < 4; r++)
                        if (j * 64 + n * 16 + quad * 4 + r > qg) st[g][n][r] = -1e30f;
            }
        }

        // online softmax (per lane: one q column, 16 key values) + P pack
        float alphaT[2][4];
#pragma unroll
        for (int g = 0; g < 2; g++) {
            float mx = st[g][0][0];
#pragma unroll
            for (int n = 0; n < 4; n++)
#pragma unroll
                for (int r = 0; r < 4; r++) mx = fmaxf(mx, st[g][n][r]);
            mx = fmaxf(mx, __shfl_xor(mx, 16));
            mx = fmaxf(mx, __shfl_xor(mx, 32));
            const float mnew = fmaxf(m[g], mx);
            const float al = __expf(m[g] - mnew);
            float sum = 0.f;
#pragma unroll
            for (int n = 0; n < 4; n++)
#pragma unroll
                for (int r = 0; r < 4; r++) {
                    const float p = __expf(st[g][n][r] - mnew);
                    st[g][n][r] = p;
                    sum += p;
                }
            sum += __shfl_xor(sum, 16);
            sum += __shfl_xor(sum, 32);
            l[g] = l[g] * al + sum;
            m[g] = mnew;
#pragma unroll
            for (int r = 0; r < 4; r++) alphaT[g][r] = __shfl(al, quad * 4 + r);
            // P^T -> P region: lane writes keys n*16+quad*4..+3 of q=g*16+mcol
#pragma unroll
            for (int n = 0; n < 4; n++) {
                const u32 lo = (u32)f2bf(st[g][n][0]) | ((u32)f2bf(st[g][n][1]) << 16);
                const u32 hi = (u32)f2bf(st[g][n][2]) | ((u32)f2bf(st[g][n][3]) << 16);
                *(uint2*)&PsW[(g * 16 + mcol) * 72 + n * 16 + quad * 4] = make_uint2(lo, hi);
            }
        }

#pragma unroll
        for (int g = 0; g < 2; g++)
#pragma unroll
            for (int dn = 0; dn < 4; dn++)
#pragma unroll
                for (int r = 0; r < 4; r++) oacc[g][dn][r] *= alphaT[g][r];

        // O += P·V  (P from own-wave LDS region; no barrier needed)
        bf16x8 pf[2][2];
#pragma unroll
        for (int g = 0; g < 2; g++) {
            pf[g][0] = *(const bf16x8*)&PsW[(g * 16 + mcol) * 72 + quad * 8];
            pf[g][1] = *(const bf16x8*)&PsW[(g * 16 + mcol) * 72 + 32 + quad * 8];
        }
#pragma unroll
        for (int dn = 0; dn < 4; dn++) {
            bf16x8 vf0 = *(const bf16x8*)&Vs[dn * 16 + mcol][quad * 8];
            bf16x8 vf1 = *(const bf16x8*)&Vs[dn * 16 + mcol][32 + quad * 8];
#pragma unroll
            for (int g = 0; g < 2; g++) {
                oacc[g][dn] = __builtin_amdgcn_mfma_f32_16x16x32_bf16(pf[g][0], vf0, oacc[g][dn], 0, 0, 0);
                oacc[g][dn] = __builtin_amdgcn_mfma_f32_16x16x32_bf16(pf[g][1], vf1, oacc[g][dn], 0, 0, 0);
            }
        }
    }

    // normalize + write O (O rows are q = quad*4+r; l lives per mcol-q -> shfl)
#pragma unroll
    for (int g = 0; g < 2; g++) {
        float linv[4];
#pragma unroll
        for (int r = 0; r < 4; r++) linv[r] = 1.f / __shfl(l[g], quad * 4 + r);
#pragma unroll
        for (int dn = 0; dn < 4; dn++)
#pragma unroll
            for (int r = 0; r < 4; r++) {
                const int row = wq0 + g * 16 + quad * 4 + r;
                o[((size_t)(b * S_ + row)) * D_ + h * DK_ + dn * 16 + mcol] =
                    f2bf(oacc[g][dn][r] * linv[r]);
            }
    }
}

// ---------------------------------------------------------------------------
extern "C" void kernel_launch(void* const* d_in, const int* in_sizes, int n_in,
                              void* d_out, int out_size, void* d_ws, size_t ws_size,
                              hipStream_t stream) {
    const float* x  = (const float*)d_in[0];
    const float* wq = (const float*)d_in[1];
    const float* wk = (const float*)d_in[2];
    const float* wv = (const float*)d_in[3];
    const float* wo = (const float*)d_in[4];
    const int*   tp = (const int*)d_in[5];
    float* out = (float*)d_out;   // fp32 output

    u16* ws = (u16*)d_ws;
    const size_t NE = (size_t)M_ * D_;       // 8.4M elems
    const size_t WE = (size_t)N_ * K_;       // 1M elems
    u16* xb  = ws;                 // bf16 x
    u16* wqb = ws + NE;
    u16* wkb = wqb + WE;
    u16* wvb = wkb + WE;
    u16* wob = wvb + WE;
    u16* qb  = wob + WE;           // roped+scaled Q
    u16* kb  = qb + NE;            // roped K
    u16* vb  = (u16*)d_out;        // V row-major (in fp32-sized d_out, dead after transpose)
    u16* vtb = (u16*)d_out + NE;   // V transposed [d][s] (dead before final GEMM)
    u16* ob  = xb;                 // attention out aliases dead xb

    dim3 blk(256);
    cvt_x<<<dim3((int)(NE / 1024)), blk, 0, stream>>>(x, xb, (int)(NE / 4));
    cvt_w4<<<dim3((int)(WE / 1024), 4), blk, 0, stream>>>(wq, wk, wv, wo, wqb, wkb, wvb, wob);

    gemm_qkv_kernel<<<dim3(N_ / 128, M_ / 128, 3), blk, 0, stream>>>(xb, wqb, wkb, wvb, qb, kb, vb);
    rope_qk<<<dim3((B_ * S_ * H_ * 32) / 256), blk, 0, stream>>>(qb, kb, tp);
    transpose_v<<<dim3(S_ / 64, H_, B_), blk, 0, stream>>>(vb, vtb);
    attn_kernel<<<dim3((S_ / 128) * H_ * B_), blk, 0, stream>>>(qb, kb, vtb, ob);
    gemm_out_kernel<<<dim3(N_ / 128, M_ / 128, 1), blk, 0, stream>>>(ob, wob, out);
}

// Round 9
// 322.378 us; speedup vs baseline: 17.4978x; 1.0106x over previous
//
#include <hip/hip_runtime.h>

#define B_ 4
#define S_ 2048
#define D_ 1024
#define H_ 16
#define DK_ 64
#define M_ (B_*S_)   // 8192 rows
#define K_ D_        // 1024
#define N_ D_        // 1024

typedef unsigned short u16;
typedef unsigned int u32;
typedef __bf16 bf16x8 __attribute__((ext_vector_type(8)));
typedef float f32x4 __attribute__((ext_vector_type(4)));

__device__ __forceinline__ u16 f2bf(float f) {
    u32 u = __builtin_bit_cast(u32, f);
    u += 0x7fff + ((u >> 16) & 1);   // round-to-nearest-even
    return (u16)(u >> 16);
}
__device__ __forceinline__ float bf2f(u16 h) {
    u32 u = ((u32)h) << 16;
    return __builtin_bit_cast(float, u);
}
// truncation-packed bf16 pair (3 ops; P in [0,1] -> bias < 2^-9 rel, OK for P)
__device__ __forceinline__ u32 pack_trunc(float a, float b) {
    return (__builtin_bit_cast(u32, a) >> 16) | (__builtin_bit_cast(u32, b) & 0xffff0000u);
}

#define GLDS16(g, l) __builtin_amdgcn_global_load_lds( \
    (__attribute__((address_space(1))) void*)(g),      \
    (__attribute__((address_space(3))) void*)(l), 16, 0, 0)

// ---------------------------------------------------------------------------
// fp32 -> bf16 converts (inputs are float32 per reference)
// ---------------------------------------------------------------------------
__global__ __launch_bounds__(256) void cvt_x(const float* __restrict__ in,
                                             u16* __restrict__ out, int n4) {
    const int i = blockIdx.x * 256 + threadIdx.x;
    if (i >= n4) return;
    const float4 f = *(const float4*)(in + (size_t)i * 4);
    u32 p0 = (u32)f2bf(f.x) | ((u32)f2bf(f.y) << 16);
    u32 p1 = (u32)f2bf(f.z) | ((u32)f2bf(f.w) << 16);
    *(uint2*)(out + (size_t)i * 4) = make_uint2(p0, p1);
}

__global__ __launch_bounds__(256) void cvt_w4(
    const float* __restrict__ w0, const float* __restrict__ w1,
    const float* __restrict__ w2, const float* __restrict__ w3,
    u16* __restrict__ o0, u16* __restrict__ o1,
    u16* __restrict__ o2, u16* __restrict__ o3) {
    const int wi = blockIdx.y;
    const float* in = (wi == 0) ? w0 : (wi == 1) ? w1 : (wi == 2) ? w2 : w3;
    u16* out       = (wi == 0) ? o0 : (wi == 1) ? o1 : (wi == 2) ? o2 : o3;
    const int i = blockIdx.x * 256 + threadIdx.x;
    const float4 f = *(const float4*)(in + (size_t)i * 4);
    u32 p0 = (u32)f2bf(f.x) | ((u32)f2bf(f.y) << 16);
    u32 p1 = (u32)f2bf(f.z) | ((u32)f2bf(f.w) << 16);
    *(uint2*)(out + (size_t)i * 4) = make_uint2(p0, p1);
}

// ---------------------------------------------------------------------------
// GEMM: C[M_][N_] = A[M_][K_] * Bm[N_][K_]^T  (bf16 in, fp32 accum)
// 128x128 tile, BK=32, 4 waves 2x2, global_load_lds width=16 staging.
// ---------------------------------------------------------------------------
template <bool F32OUT>
__device__ __forceinline__ void gemm_tile(const u16* __restrict__ A,
                                          const u16* __restrict__ Bm,
                                          void* __restrict__ Cv) {
    __shared__ u16 As[128 * 32];
    __shared__ u16 Bs[128 * 32];
    const int tid  = threadIdx.x;
    const int wave = tid >> 6, lane = tid & 63;
    const int m0 = blockIdx.y * 128, n0 = blockIdx.x * 128;
    const int wm = wave & 1, wn = wave >> 1;
    const int quad = lane >> 4, mcol = lane & 15;

    const int c0 = wave, c1 = wave + 4;
    const int r0 = c0 * 16 + (lane >> 2), r1 = c1 * 16 + (lane >> 2);
    const int kb = (lane & 3) * 8;
    const u16* ga0 = A  + (size_t)(m0 + r0) * K_ + kb;
    const u16* ga1 = A  + (size_t)(m0 + r1) * K_ + kb;
    const u16* gb0 = Bm + (size_t)(n0 + r0) * K_ + kb;
    const u16* gb1 = Bm + (size_t)(n0 + r1) * K_ + kb;
    u16* la0 = &As[c0 * 512];
    u16* la1 = &As[c1 * 512];
    u16* lb0 = &Bs[c0 * 512];
    u16* lb1 = &Bs[c1 * 512];

    f32x4 acc[4][4];
#pragma unroll
    for (int i = 0; i < 4; i++)
#pragma unroll
        for (int j = 0; j < 4; j++) acc[i][j] = f32x4{0.f, 0.f, 0.f, 0.f};

    for (int kt = 0; kt < K_; kt += 32) {
        __syncthreads();
        GLDS16(ga0, la0); GLDS16(ga1, la1);
        GLDS16(gb0, lb0); GLDS16(gb1, lb1);
        ga0 += 32; ga1 += 32; gb0 += 32; gb1 += 32;
        __syncthreads();

        bf16x8 af[4], bfr[4];
#pragma unroll
        for (int i = 0; i < 4; i++) {
            af[i]  = *(const bf16x8*)&As[(size_t)(wm * 64 + i * 16 + mcol) * 32 + quad * 8];
            bfr[i] = *(const bf16x8*)&Bs[(size_t)(wn * 64 + i * 16 + mcol) * 32 + quad * 8];
        }
#pragma unroll
        for (int i = 0; i < 4; i++)
#pragma unroll
            for (int j = 0; j < 4; j++)
                acc[i][j] = __builtin_amdgcn_mfma_f32_16x16x32_bf16(
                    af[i], bfr[j], acc[i][j], 0, 0, 0);
    }

    // epilogue: C/D layout row=(lane>>4)*4+reg, col=lane&15
#pragma unroll
    for (int i = 0; i < 4; i++) {
        const int row = m0 + wm * 64 + i * 16 + quad * 4;
#pragma unroll
        for (int j = 0; j < 4; j++) {
            const int col = n0 + wn * 64 + j * 16 + mcol;
#pragma unroll
            for (int r = 0; r < 4; r++) {
                if constexpr (F32OUT)
                    ((float*)Cv)[(size_t)(row + r) * N_ + col] = acc[i][j][r];
                else
                    ((u16*)Cv)[(size_t)(row + r) * N_ + col] = f2bf(acc[i][j][r]);
            }
        }
    }
}

__global__ __launch_bounds__(256) void gemm_qkv_kernel(
    const u16* __restrict__ x,
    const u16* __restrict__ wq, const u16* __restrict__ wk, const u16* __restrict__ wv,
    u16* __restrict__ q, u16* __restrict__ k, u16* __restrict__ v) {
    const u16* Bm; u16* C;
    if (blockIdx.z == 0)      { Bm = wq; C = q; }
    else if (blockIdx.z == 1) { Bm = wk; C = k; }
    else                      { Bm = wv; C = v; }
    gemm_tile<false>(x, Bm, C);
}

__global__ __launch_bounds__(256) void gemm_out_kernel(
    const u16* __restrict__ o, const u16* __restrict__ wo, float* __restrict__ out) {
    gemm_tile<true>(o, wo, out);
}

// ---------------------------------------------------------------------------
// RoPE (interleaved) in-place; Q additionally scaled by 0.125*log2(e) so the
// attention softmax can run in exp2 domain (native v_exp_f32 base).
// ---------------------------------------------------------------------------
__global__ __launch_bounds__(256) void rope_qk(u16* __restrict__ q,
                                               u16* __restrict__ k,
                                               const int* __restrict__ pos) {
    const int idx = blockIdx.x * 256 + threadIdx.x;
    const int i = idx & 31;
    const int h = (idx >> 5) & (H_ - 1);
    const int s = (idx >> 9) & (S_ - 1);
    const int b = idx >> 20;
    const float p = (float)pos[s];
    // theta^(-i/32) = 2^(-i/32 * log2(10000))
    const float inv = exp2f((float)i * (-13.287712379549449f / 32.f));
    const float ang = p * inv;
    float sn, cs;
    __sincosf(ang, &sn, &cs);
    const float QSC = 0.125f * 1.4426950408889634f;   // 1/sqrt(DK) * log2(e)
    const size_t off = ((size_t)(b * S_ + s)) * D_ + h * DK_ + 2 * i;
    {
        float x1 = bf2f(q[off]), x2 = bf2f(q[off + 1]);
        q[off]     = f2bf((x1 * cs - x2 * sn) * QSC);
        q[off + 1] = f2bf((x1 * sn + x2 * cs) * QSC);
    }
    {
        float x1 = bf2f(k[off]), x2 = bf2f(k[off + 1]);
        k[off]     = f2bf(x1 * cs - x2 * sn);
        k[off + 1] = f2bf(x1 * sn + x2 * cs);
    }
}

// ---------------------------------------------------------------------------
// Transpose V: v[b*S+s][h*64+d] -> vt[((b*H+h)*64+d)*S + s]
// ---------------------------------------------------------------------------
__global__ __launch_bounds__(256) void transpose_v(const u16* __restrict__ v,
                                                   u16* __restrict__ vt) {
    __shared__ u16 t[64][72];
    const int tid = threadIdx.x;
    const int s0 = blockIdx.x * 64, h = blockIdx.y, b = blockIdx.z;
    const int rr = tid >> 3, ch = tid & 7;
    *(uint4*)&t[rr][ch * 8] =
        *(const uint4*)(v + ((size_t)(b * S_ + s0 + rr)) * D_ + h * DK_ + ch * 8);
    *(uint4*)&t[rr + 32][ch * 8] =
        *(const uint4*)(v + ((size_t)(b * S_ + s0 + rr + 32)) * D_ + h * DK_ + ch * 8);
    __syncthreads();
#pragma unroll
    for (int pass = 0; pass < 2; pass++) {
        const int d = rr + pass * 32;
        uint4 u;
        u16* tp = (u16*)&u;
#pragma unroll
        for (int j = 0; j < 8; j++) tp[j] = t[ch * 8 + j][d];
        *(uint4*)(vt + ((size_t)((b * H_ + h) * DK_ + d)) * S_ + s0 + ch * 8) = u;
    }
}

// ---------------------------------------------------------------------------
// Causal flash attention, MFMA, S^T formulation, exp2-domain softmax.
// Flat 1024-block grid, qt = flat>>6 (load-balance swizzle). Block = 128 q
// rows (4 waves x 32), 64-key tiles. Q pre-scaled by 0.125*log2e.
// ---------------------------------------------------------------------------
__global__ __launch_bounds__(256) void attn_kernel(
    const u16* __restrict__ q, const u16* __restrict__ k,
    const u16* __restrict__ vt, u16* __restrict__ o) {
    __shared__ u16 Qs[128][72];      // after init, wave w's rows [w*32,+32) = P region
    __shared__ u16 Ks[64][72];       // [key][d]
    __shared__ u16 Vs[64][72];       // [d][key]

    const int tid = threadIdx.x, wave = tid >> 6, lane = tid & 63;
    const int flat = blockIdx.x;
    const int qt = flat >> 6;
    const int h = flat & (H_ - 1);
    const int b = (flat >> 4) & 3;
    const int q0 = qt * 128;
    const int quad = lane >> 4, mcol = lane & 15;

    // stage Q tile (128 x 64)
    {
        const int rr = tid >> 1, cc = (tid & 1) * 32;
        const u16* src = q + ((size_t)(b * S_ + q0 + rr)) * D_ + h * DK_ + cc;
        u16* dst = &Qs[rr][cc];
        *(uint4*)(dst)      = *(const uint4*)(src);
        *(uint4*)(dst + 8)  = *(const uint4*)(src + 8);
        *(uint4*)(dst + 16) = *(const uint4*)(src + 16);
        *(uint4*)(dst + 24) = *(const uint4*)(src + 24);
    }
    __syncthreads();
    bf16x8 qf[2][2];
#pragma unroll
    for (int g = 0; g < 2; g++) {
        qf[g][0] = *(const bf16x8*)&Qs[wave * 32 + g * 16 + mcol][quad * 8];
        qf[g][1] = *(const bf16x8*)&Qs[wave * 32 + g * 16 + mcol][32 + quad * 8];
    }
    u16* PsW = &Qs[wave * 32][0];   // this wave's private P region [32][72]

    float m[2] = {-1e30f, -1e30f}, l[2] = {0.f, 0.f};
    f32x4 oacc[2][4];
#pragma unroll
    for (int g = 0; g < 2; g++)
#pragma unroll
        for (int dn = 0; dn < 4; dn++) oacc[g][dn] = f32x4{0.f, 0.f, 0.f, 0.f};

    const int rr2 = tid >> 2, ch2 = (tid & 3) * 16;   // K/V staging coords
    const u16* krow = k + ((size_t)(b * S_ + rr2)) * D_ + h * DK_ + ch2;
    const u16* vrow = vt + ((size_t)((b * H_ + h) * DK_ + rr2)) * S_ + ch2;
    const int wq0 = q0 + wave * 32;
    const int jmax = 2 * qt + 1;

    uint4 kr0 = *(const uint4*)(krow);
    uint4 kr1 = *(const uint4*)(krow + 8);
    uint4 vr0 = *(const uint4*)(vrow);
    uint4 vr1 = *(const uint4*)(vrow + 8);

    for (int j = 0; j <= jmax; j++) {
        __syncthreads();
        *(uint4*)&Ks[rr2][ch2]     = kr0;
        *(uint4*)&Ks[rr2][ch2 + 8] = kr1;
        *(uint4*)&Vs[rr2][ch2]     = vr0;
        *(uint4*)&Vs[rr2][ch2 + 8] = vr1;
        __syncthreads();

        if (j < jmax) {
            kr0 = *(const uint4*)(krow + (size_t)(j + 1) * 64 * D_);
            kr1 = *(const uint4*)(krow + (size_t)(j + 1) * 64 * D_ + 8);
            vr0 = *(const uint4*)(vrow + (j + 1) * 64);
            vr1 = *(const uint4*)(vrow + (j + 1) * 64 + 8);
        }

        if (j * 64 > wq0 + 31) continue;   // fully masked for this wave

        // S^T = K·Q^T (scores already in log2 domain via Q pre-scale)
        f32x4 st[2][4];
#pragma unroll
        for (int n = 0; n < 4; n++) {
            bf16x8 kf0 = *(const bf16x8*)&Ks[n * 16 + mcol][quad * 8];
            bf16x8 kf1 = *(const bf16x8*)&Ks[n * 16 + mcol][32 + quad * 8];
            f32x4 z0 = f32x4{0.f, 0.f, 0.f, 0.f};
            z0 = __builtin_amdgcn_mfma_f32_16x16x32_bf16(kf0, qf[0][0], z0, 0, 0, 0);
            z0 = __builtin_amdgcn_mfma_f32_16x16x32_bf16(kf1, qf[0][1], z0, 0, 0, 0);
            st[0][n] = z0;
            f32x4 z1 = f32x4{0.f, 0.f, 0.f, 0.f};
            z1 = __builtin_amdgcn_mfma_f32_16x16x32_bf16(kf0, qf[1][0], z1, 0, 0, 0);
            z1 = __builtin_amdgcn_mfma_f32_16x16x32_bf16(kf1, qf[1][1], z1, 0, 0, 0);
            st[1][n] = z1;
        }

        if (j * 64 + 63 > wq0) {
#pragma unroll
            for (int g = 0; g < 2; g++) {
                const int qg = wq0 + g * 16 + mcol;
#pragma unroll
                for (int n = 0; n < 4; n++)
#pragma unroll
                    for (int r = 0; r < 4; r++)
                        if (j * 64 + n * 16 + quad * 4 + r > qg) st[g][n][r] = -1e30f;
            }
        }

        // online softmax in exp2 domain + truncation-packed P
        float alphaT[2][4];
#pragma unroll
        for (int g = 0; g < 2; g++) {
            float mx = st[g][0][0];
#pragma unroll
            for (int n = 0; n < 4; n++)
#pragma unroll
                for (int r = 0; r < 4; r++) mx = fmaxf(mx, st[g][n][r]);
            mx = fmaxf(mx, __shfl_xor(mx, 16));
            mx = fmaxf(mx, __shfl_xor(mx, 32));
            const float mnew = fmaxf(m[g], mx);
            const float al = exp2f(m[g] - mnew);
            float sum = 0.f;
#pragma unroll
            for (int n = 0; n < 4; n++)
#pragma unroll
                for (int r = 0; r < 4; r++) {
                    const float p = exp2f(st[g][n][r] - mnew);
                    st[g][n][r] = p;
                    sum += p;
                }
            sum += __shfl_xor(sum, 16);
            sum += __shfl_xor(sum, 32);
            l[g] = l[g] * al + sum;
            m[g] = mnew;
#pragma unroll
            for (int r = 0; r < 4; r++) alphaT[g][r] = __shfl(al, quad * 4 + r);
#pragma unroll
            for (int n = 0; n < 4; n++) {
                const u32 lo = pack_trunc(st[g][n][0], st[g][n][1]);
                const u32 hi = pack_trunc(st[g][n][2], st[g][n][3]);
                *(uint2*)&PsW[(g * 16 + mcol) * 72 + n * 16 + quad * 4] = make_uint2(lo, hi);
            }
        }

#pragma unroll
        for (int g = 0; g < 2; g++)
#pragma unroll
            for (int dn = 0; dn < 4; dn++)
#pragma unroll
                for (int r = 0; r < 4; r++) oacc[g][dn][r] *= alphaT[g][r];

        // O += P·V  (P from own-wave LDS region; no barrier needed)
        bf16x8 pf[2][2];
#pragma unroll
        for (int g = 0; g < 2; g++) {
            pf[g][0] = *(const bf16x8*)&PsW[(g * 16 + mcol) * 72 + quad * 8];
            pf[g][1] = *(const bf16x8*)&PsW[(g * 16 + mcol) * 72 + 32 + quad * 8];
        }
#pragma unroll
        for (int dn = 0; dn < 4; dn++) {
            bf16x8 vf0 = *(const bf16x8*)&Vs[dn * 16 + mcol][quad * 8];
            bf16x8 vf1 = *(const bf16x8*)&Vs[dn * 16 + mcol][32 + quad * 8];
#pragma unroll
            for (int g = 0; g < 2; g++) {
                oacc[g][dn] = __builtin_amdgcn_mfma_f32_16x16x32_bf16(pf[g][0], vf0, oacc[g][dn], 0, 0, 0);
                oacc[g][dn] = __builtin_amdgcn_mfma_f32_16x16x32_bf16(pf[g][1], vf1, oacc[g][dn], 0, 0, 0);
            }
        }
    }

    // normalize + write O
#pragma unroll
    for (int g = 0; g < 2; g++) {
        float linv[4];
#pragma unroll
        for (int r = 0; r < 4; r++) linv[r] = 1.f / __shfl(l[g], quad * 4 + r);
#pragma unroll
        for (int dn = 0; dn < 4; dn++)
#pragma unroll
            for (int r = 0; r < 4; r++) {
                const int row = wq0 + g * 16 + quad * 4 + r;
                o[((size_t)(b * S_ + row)) * D_ + h * DK_ + dn * 16 + mcol] =
                    f2bf(oacc[g][dn][r] * linv[r]);
            }
    }
}

// ---------------------------------------------------------------------------
extern "C" void kernel_launch(void* const* d_in, const int* in_sizes, int n_in,
                              void* d_out, int out_size, void* d_ws, size_t ws_size,
                              hipStream_t stream) {
    const float* x  = (const float*)d_in[0];
    const float* wq = (const float*)d_in[1];
    const float* wk = (const float*)d_in[2];
    const float* wv = (const float*)d_in[3];
    const float* wo = (const float*)d_in[4];
    const int*   tp = (const int*)d_in[5];
    float* out = (float*)d_out;

    u16* ws = (u16*)d_ws;
    const size_t NE = (size_t)M_ * D_;
    const size_t WE = (size_t)N_ * K_;
    u16* xb  = ws;
    u16* wqb = ws + NE;
    u16* wkb = wqb + WE;
    u16* wvb = wkb + WE;
    u16* wob = wvb + WE;
    u16* qb  = wob + WE;
    u16* kb  = qb + NE;
    u16* vb  = (u16*)d_out;        // V row-major (in fp32-sized d_out)
    u16* vtb = (u16*)d_out + NE;   // V transposed [d][s]
    u16* ob  = xb;                 // attention out aliases dead xb

    dim3 blk(256);
    cvt_x<<<dim3((int)(NE / 1024)), blk, 0, stream>>>(x, xb, (int)(NE / 4));
    cvt_w4<<<dim3((int)(WE / 1024), 4), blk, 0, stream>>>(wq, wk, wv, wo, wqb, wkb, wvb, wob);

    gemm_qkv_kernel<<<dim3(N_ / 128, M_ / 128, 3), blk, 0, stream>>>(xb, wqb, wkb, wvb, qb, kb, vb);
    rope_qk<<<dim3((B_ * S_ * H_ * 32) / 256), blk, 0, stream>>>(qb, kb, tp);
    transpose_v<<<dim3(S_ / 64, H_, B_), blk, 0, stream>>>(vb, vtb);
    attn_kernel<<<dim3((S_ / 128) * H_ * B_), blk, 0, stream>>>(qb, kb, vtb, ob);
    gemm_out_kernel<<<dim3(N_ / 128, M_ / 128, 1), blk, 0, stream>>>(ob, wob, out);
}

// Round 10
// 317.557 us; speedup vs baseline: 17.7634x; 1.0152x over previous
//
#include <hip/hip_runtime.h>

#define B_ 4
#define S_ 2048
#define D_ 1024
#define H_ 16
#define DK_ 64
#define M_ (B_*S_)   // 8192 rows
#define K_ D_        // 1024
#define N_ D_        // 1024

typedef unsigned short u16;
typedef unsigned int u32;
typedef __bf16 bf16x8 __attribute__((ext_vector_type(8)));
typedef float f32x4 __attribute__((ext_vector_type(4)));

__device__ __forceinline__ u16 f2bf(float f) {
    u32 u = __builtin_bit_cast(u32, f);
    u += 0x7fff + ((u >> 16) & 1);   // round-to-nearest-even
    return (u16)(u >> 16);
}
__device__ __forceinline__ float bf2f(u16 h) {
    u32 u = ((u32)h) << 16;
    return __builtin_bit_cast(float, u);
}
// truncation-packed bf16 pair (3 ops; P in [0,1] -> bias < 2^-9 rel, OK for P)
__device__ __forceinline__ u32 pack_trunc(float a, float b) {
    return (__builtin_bit_cast(u32, a) >> 16) | (__builtin_bit_cast(u32, b) & 0xffff0000u);
}

#define GLDS16(g, l) __builtin_amdgcn_global_load_lds( \
    (__attribute__((address_space(1))) void*)(g),      \
    (__attribute__((address_space(3))) void*)(l), 16, 0, 0)

// ---------------------------------------------------------------------------
// fp32 -> bf16 converts (inputs are float32 per reference)
// ---------------------------------------------------------------------------
__global__ __launch_bounds__(256) void cvt_x(const float* __restrict__ in,
                                             u16* __restrict__ out, int n4) {
    const int i = blockIdx.x * 256 + threadIdx.x;
    if (i >= n4) return;
    const float4 f = *(const float4*)(in + (size_t)i * 4);
    u32 p0 = (u32)f2bf(f.x) | ((u32)f2bf(f.y) << 16);
    u32 p1 = (u32)f2bf(f.z) | ((u32)f2bf(f.w) << 16);
    *(uint2*)(out + (size_t)i * 4) = make_uint2(p0, p1);
}

__global__ __launch_bounds__(256) void cvt_w4(
    const float* __restrict__ w0, const float* __restrict__ w1,
    const float* __restrict__ w2, const float* __restrict__ w3,
    u16* __restrict__ o0, u16* __restrict__ o1,
    u16* __restrict__ o2, u16* __restrict__ o3) {
    const int wi = blockIdx.y;
    const float* in = (wi == 0) ? w0 : (wi == 1) ? w1 : (wi == 2) ? w2 : w3;
    u16* out       = (wi == 0) ? o0 : (wi == 1) ? o1 : (wi == 2) ? o2 : o3;
    const int i = blockIdx.x * 256 + threadIdx.x;
    const float4 f = *(const float4*)(in + (size_t)i * 4);
    u32 p0 = (u32)f2bf(f.x) | ((u32)f2bf(f.y) << 16);
    u32 p1 = (u32)f2bf(f.z) | ((u32)f2bf(f.w) << 16);
    *(uint2*)(out + (size_t)i * 4) = make_uint2(p0, p1);
}

// ---------------------------------------------------------------------------
// GEMM: C = A * Bm^T  (bf16 in, fp32 accum), 128x128 tile, BK=32, 4 waves,
// global_load_lds width=16 staging.
// MODE 0: bf16 row-major C.  MODE 1: fp32 row-major C.
// MODE 2: bf16 V-transposed store: C[row][col] -> vt[((b*H+h)*64+d)*S + s]
//         (h=col>>6, d=col&63, b=row>>11, s=row&2047); the 4 acc regs of a
//         frag are 4 consecutive s at fixed d -> contiguous uint2 store.
// ---------------------------------------------------------------------------
template <int MODE>
__device__ __forceinline__ void gemm_tile(const u16* __restrict__ A,
                                          const u16* __restrict__ Bm,
                                          void* __restrict__ Cv) {
    __shared__ u16 As[128 * 32];
    __shared__ u16 Bs[128 * 32];
    const int tid  = threadIdx.x;
    const int wave = tid >> 6, lane = tid & 63;
    const int m0 = blockIdx.y * 128, n0 = blockIdx.x * 128;
    const int wm = wave & 1, wn = wave >> 1;
    const int quad = lane >> 4, mcol = lane & 15;

    const int c0 = wave, c1 = wave + 4;
    const int r0 = c0 * 16 + (lane >> 2), r1 = c1 * 16 + (lane >> 2);
    const int kb = (lane & 3) * 8;
    const u16* ga0 = A  + (size_t)(m0 + r0) * K_ + kb;
    const u16* ga1 = A  + (size_t)(m0 + r1) * K_ + kb;
    const u16* gb0 = Bm + (size_t)(n0 + r0) * K_ + kb;
    const u16* gb1 = Bm + (size_t)(n0 + r1) * K_ + kb;
    u16* la0 = &As[c0 * 512];
    u16* la1 = &As[c1 * 512];
    u16* lb0 = &Bs[c0 * 512];
    u16* lb1 = &Bs[c1 * 512];

    f32x4 acc[4][4];
#pragma unroll
    for (int i = 0; i < 4; i++)
#pragma unroll
        for (int j = 0; j < 4; j++) acc[i][j] = f32x4{0.f, 0.f, 0.f, 0.f};

    for (int kt = 0; kt < K_; kt += 32) {
        __syncthreads();
        GLDS16(ga0, la0); GLDS16(ga1, la1);
        GLDS16(gb0, lb0); GLDS16(gb1, lb1);
        ga0 += 32; ga1 += 32; gb0 += 32; gb1 += 32;
        __syncthreads();

        bf16x8 af[4], bfr[4];
#pragma unroll
        for (int i = 0; i < 4; i++) {
            af[i]  = *(const bf16x8*)&As[(size_t)(wm * 64 + i * 16 + mcol) * 32 + quad * 8];
            bfr[i] = *(const bf16x8*)&Bs[(size_t)(wn * 64 + i * 16 + mcol) * 32 + quad * 8];
        }
#pragma unroll
        for (int i = 0; i < 4; i++)
#pragma unroll
            for (int j = 0; j < 4; j++)
                acc[i][j] = __builtin_amdgcn_mfma_f32_16x16x32_bf16(
                    af[i], bfr[j], acc[i][j], 0, 0, 0);
    }

    // epilogue: C/D layout row=(lane>>4)*4+reg, col=lane&15
#pragma unroll
    for (int i = 0; i < 4; i++) {
        const int row = m0 + wm * 64 + i * 16 + quad * 4;
#pragma unroll
        for (int j = 0; j < 4; j++) {
            const int col = n0 + wn * 64 + j * 16 + mcol;
            if constexpr (MODE == 2) {
                const int hh = col >> 6, dd = col & 63;
                const int bb = row >> 11, ss = row & 2047;
                const u32 lo = (u32)f2bf(acc[i][j][0]) | ((u32)f2bf(acc[i][j][1]) << 16);
                const u32 hi = (u32)f2bf(acc[i][j][2]) | ((u32)f2bf(acc[i][j][3]) << 16);
                *(uint2*)((u16*)Cv + ((size_t)((bb * H_ + hh) * DK_ + dd)) * S_ + ss) =
                    make_uint2(lo, hi);
            } else {
#pragma unroll
                for (int r = 0; r < 4; r++) {
                    if constexpr (MODE == 1)
                        ((float*)Cv)[(size_t)(row + r) * N_ + col] = acc[i][j][r];
                    else
                        ((u16*)Cv)[(size_t)(row + r) * N_ + col] = f2bf(acc[i][j][r]);
                }
            }
        }
    }
}

__global__ __launch_bounds__(256) void gemm_qk_kernel(
    const u16* __restrict__ x,
    const u16* __restrict__ wq, const u16* __restrict__ wk,
    u16* __restrict__ q, u16* __restrict__ k) {
    const u16* Bm = (blockIdx.z == 0) ? wq : wk;
    u16* C        = (blockIdx.z == 0) ? q  : k;
    gemm_tile<0>(x, Bm, C);
}

__global__ __launch_bounds__(256) void gemm_v_kernel(
    const u16* __restrict__ x, const u16* __restrict__ wv, u16* __restrict__ vt) {
    gemm_tile<2>(x, wv, vt);
}

__global__ __launch_bounds__(256) void gemm_out_kernel(
    const u16* __restrict__ o, const u16* __restrict__ wo, float* __restrict__ out) {
    gemm_tile<1>(o, wo, out);
}

// ---------------------------------------------------------------------------
// RoPE (interleaved) in-place; Q additionally scaled by 1/8 (folds the
// 1/sqrt(DK) score scale into Q).
// ---------------------------------------------------------------------------
__global__ __launch_bounds__(256) void rope_qk(u16* __restrict__ q,
                                               u16* __restrict__ k,
                                               const int* __restrict__ pos) {
    const int idx = blockIdx.x * 256 + threadIdx.x;
    const int i = idx & 31;
    const int h = (idx >> 5) & (H_ - 1);
    const int s = (idx >> 9) & (S_ - 1);
    const int b = idx >> 20;
    const float p = (float)pos[s];
    // theta^(-i/32) = 2^(-i/32 * log2(10000))
    const float inv = exp2f((float)i * (-13.287712379549449f / 32.f));
    const float ang = p * inv;
    float sn, cs;
    __sincosf(ang, &sn, &cs);
    const float QSC = 0.125f;   // 1/sqrt(DK)
    const size_t off = ((size_t)(b * S_ + s)) * D_ + h * DK_ + 2 * i;
    {
        float x1 = bf2f(q[off]), x2 = bf2f(q[off + 1]);
        q[off]     = f2bf((x1 * cs - x2 * sn) * QSC);
        q[off + 1] = f2bf((x1 * sn + x2 * cs) * QSC);
    }
    {
        float x1 = bf2f(k[off]), x2 = bf2f(k[off + 1]);
        k[off]     = f2bf(x1 * cs - x2 * sn);
        k[off + 1] = f2bf(x1 * sn + x2 * cs);
    }
}

// ---------------------------------------------------------------------------
// Causal flash attention, MFMA, S^T formulation, __expf softmax (e-domain).
// Flat 1024-block grid, qt = flat>>6 (load-balance swizzle). Block = 128 q
// rows (4 waves x 32), 64-key tiles. Q pre-scaled by 1/8.
// ---------------------------------------------------------------------------
__global__ __launch_bounds__(256) void attn_kernel(
    const u16* __restrict__ q, const u16* __restrict__ k,
    const u16* __restrict__ vt, u16* __restrict__ o) {
    __shared__ u16 Qs[128][72];      // after init, wave w's rows [w*32,+32) = P region
    __shared__ u16 Ks[64][72];       // [key][d]
    __shared__ u16 Vs[64][72];       // [d][key]

    const int tid = threadIdx.x, wave = tid >> 6, lane = tid & 63;
    const int flat = blockIdx.x;
    const int qt = flat >> 6;
    const int h = flat & (H_ - 1);
    const int b = (flat >> 4) & 3;
    const int q0 = qt * 128;
    const int quad = lane >> 4, mcol = lane & 15;

    // stage Q tile (128 x 64)
    {
        const int rr = tid >> 1, cc = (tid & 1) * 32;
        const u16* src = q + ((size_t)(b * S_ + q0 + rr)) * D_ + h * DK_ + cc;
        u16* dst = &Qs[rr][cc];
        *(uint4*)(dst)      = *(const uint4*)(src);
        *(uint4*)(dst + 8)  = *(const uint4*)(src + 8);
        *(uint4*)(dst + 16) = *(const uint4*)(src + 16);
        *(uint4*)(dst + 24) = *(const uint4*)(src + 24);
    }
    __syncthreads();
    bf16x8 qf[2][2];
#pragma unroll
    for (int g = 0; g < 2; g++) {
        qf[g][0] = *(const bf16x8*)&Qs[wave * 32 + g * 16 + mcol][quad * 8];
        qf[g][1] = *(const bf16x8*)&Qs[wave * 32 + g * 16 + mcol][32 + quad * 8];
    }
    u16* PsW = &Qs[wave * 32][0];   // this wave's private P region [32][72]

    float m[2] = {-1e30f, -1e30f}, l[2] = {0.f, 0.f};
    f32x4 oacc[2][4];
#pragma unroll
    for (int g = 0; g < 2; g++)
#pragma unroll
        for (int dn = 0; dn < 4; dn++) oacc[g][dn] = f32x4{0.f, 0.f, 0.f, 0.f};

    const int rr2 = tid >> 2, ch2 = (tid & 3) * 16;   // K/V staging coords
    const u16* krow = k + ((size_t)(b * S_ + rr2)) * D_ + h * DK_ + ch2;
    const u16* vrow = vt + ((size_t)((b * H_ + h) * DK_ + rr2)) * S_ + ch2;
    const int wq0 = q0 + wave * 32;
    const int jmax = 2 * qt + 1;

    uint4 kr0 = *(const uint4*)(krow);
    uint4 kr1 = *(const uint4*)(krow + 8);
    uint4 vr0 = *(const uint4*)(vrow);
    uint4 vr1 = *(const uint4*)(vrow + 8);

    for (int j = 0; j <= jmax; j++) {
        __syncthreads();
        *(uint4*)&Ks[rr2][ch2]     = kr0;
        *(uint4*)&Ks[rr2][ch2 + 8] = kr1;
        *(uint4*)&Vs[rr2][ch2]     = vr0;
        *(uint4*)&Vs[rr2][ch2 + 8] = vr1;
        __syncthreads();

        if (j < jmax) {
            kr0 = *(const uint4*)(krow + (size_t)(j + 1) * 64 * D_);
            kr1 = *(const uint4*)(krow + (size_t)(j + 1) * 64 * D_ + 8);
            vr0 = *(const uint4*)(vrow + (j + 1) * 64);
            vr1 = *(const uint4*)(vrow + (j + 1) * 64 + 8);
        }

        if (j * 64 > wq0 + 31) continue;   // fully masked for this wave

        // S^T = K·Q^T
        f32x4 st[2][4];
#pragma unroll
        for (int n = 0; n < 4; n++) {
            bf16x8 kf0 = *(const bf16x8*)&Ks[n * 16 + mcol][quad * 8];
            bf16x8 kf1 = *(const bf16x8*)&Ks[n * 16 + mcol][32 + quad * 8];
            f32x4 z0 = f32x4{0.f, 0.f, 0.f, 0.f};
            z0 = __builtin_amdgcn_mfma_f32_16x16x32_bf16(kf0, qf[0][0], z0, 0, 0, 0);
            z0 = __builtin_amdgcn_mfma_f32_16x16x32_bf16(kf1, qf[0][1], z0, 0, 0, 0);
            st[0][n] = z0;
            f32x4 z1 = f32x4{0.f, 0.f, 0.f, 0.f};
            z1 = __builtin_amdgcn_mfma_f32_16x16x32_bf16(kf0, qf[1][0], z1, 0, 0, 0);
            z1 = __builtin_amdgcn_mfma_f32_16x16x32_bf16(kf1, qf[1][1], z1, 0, 0, 0);
            st[1][n] = z1;
        }

        if (j * 64 + 63 > wq0) {
#pragma unroll
            for (int g = 0; g < 2; g++) {
                const int qg = wq0 + g * 16 + mcol;
#pragma unroll
                for (int n = 0; n < 4; n++)
#pragma unroll
                    for (int r = 0; r < 4; r++)
                        if (j * 64 + n * 16 + quad * 4 + r > qg) st[g][n][r] = -1e30f;
            }
        }

        // online softmax (__expf) + truncation-packed P
        float alphaT[2][4];
#pragma unroll
        for (int g = 0; g < 2; g++) {
            float mx = st[g][0][0];
#pragma unroll
            for (int n = 0; n < 4; n++)
#pragma unroll
                for (int r = 0; r < 4; r++) mx = fmaxf(mx, st[g][n][r]);
            mx = fmaxf(mx, __shfl_xor(mx, 16));
            mx = fmaxf(mx, __shfl_xor(mx, 32));
            const float mnew = fmaxf(m[g], mx);
            const float al = __expf(m[g] - mnew);
            float sum = 0.f;
#pragma unroll
            for (int n = 0; n < 4; n++)
#pragma unroll
                for (int r = 0; r < 4; r++) {
                    const float p = __expf(st[g][n][r] - mnew);
                    st[g][n][r] = p;
                    sum += p;
                }
            sum += __shfl_xor(sum, 16);
            sum += __shfl_xor(sum, 32);
            l[g] = l[g] * al + sum;
            m[g] = mnew;
#pragma unroll
            for (int r = 0; r < 4; r++) alphaT[g][r] = __shfl(al, quad * 4 + r);
#pragma unroll
            for (int n = 0; n < 4; n++) {
                const u32 lo = pack_trunc(st[g][n][0], st[g][n][1]);
                const u32 hi = pack_trunc(st[g][n][2], st[g][n][3]);
                *(uint2*)&PsW[(g * 16 + mcol) * 72 + n * 16 + quad * 4] = make_uint2(lo, hi);
            }
        }

#pragma unroll
        for (int g = 0; g < 2; g++)
#pragma unroll
            for (int dn = 0; dn < 4; dn++)
#pragma unroll
                for (int r = 0; r < 4; r++) oacc[g][dn][r] *= alphaT[g][r];

        // O += P·V  (P from own-wave LDS region; no barrier needed)
        bf16x8 pf[2][2];
#pragma unroll
        for (int g = 0; g < 2; g++) {
            pf[g][0] = *(const bf16x8*)&PsW[(g * 16 + mcol) * 72 + quad * 8];
            pf[g][1] = *(const bf16x8*)&PsW[(g * 16 + mcol) * 72 + 32 + quad * 8];
        }
#pragma unroll
        for (int dn = 0; dn < 4; dn++) {
            bf16x8 vf0 = *(const bf16x8*)&Vs[dn * 16 + mcol][quad * 8];
            bf16x8 vf1 = *(const bf16x8*)&Vs[dn * 16 + mcol][32 + quad * 8];
#pragma unroll
            for (int g = 0; g < 2; g++) {
                oacc[g][dn] = __builtin_amdgcn_mfma_f32_16x16x32_bf16(pf[g][0], vf0, oacc[g][dn], 0, 0, 0);
                oacc[g][dn] = __builtin_amdgcn_mfma_f32_16x16x32_bf16(pf[g][1], vf1, oacc[g][dn], 0, 0, 0);
            }
        }
    }

    // normalize + write O
#pragma unroll
    for (int g = 0; g < 2; g++) {
        float linv[4];
#pragma unroll
        for (int r = 0; r < 4; r++) linv[r] = 1.f / __shfl(l[g], quad * 4 + r);
#pragma unroll
        for (int dn = 0; dn < 4; dn++)
#pragma unroll
            for (int r = 0; r < 4; r++) {
                const int row = wq0 + g * 16 + quad * 4 + r;
                o[((size_t)(b * S_ + row)) * D_ + h * DK_ + dn * 16 + mcol] =
                    f2bf(oacc[g][dn][r] * linv[r]);
            }
    }
}

// ---------------------------------------------------------------------------
extern "C" void kernel_launch(void* const* d_in, const int* in_sizes, int n_in,
                              void* d_out, int out_size, void* d_ws, size_t ws_size,
                              hipStream_t stream) {
    const float* x  = (const float*)d_in[0];
    const float* wq = (const float*)d_in[1];
    const float* wk = (const float*)d_in[2];
    const float* wv = (const float*)d_in[3];
    const float* wo = (const float*)d_in[4];
    const int*   tp = (const int*)d_in[5];
    float* out = (float*)d_out;

    u16* ws = (u16*)d_ws;
    const size_t NE = (size_t)M_ * D_;
    const size_t WE = (size_t)N_ * K_;
    u16* xb  = ws;
    u16* wqb = ws + NE;
    u16* wkb = wqb + WE;
    u16* wvb = wkb + WE;
    u16* wob = wvb + WE;
    u16* qb  = wob + WE;
    u16* kb  = qb + NE;
    u16* vtb = (u16*)d_out;   // V transposed [d][s], parked in fp32-sized d_out
    u16* ob  = xb;            // attention out aliases dead xb

    dim3 blk(256);
    cvt_x<<<dim3((int)(NE / 1024)), blk, 0, stream>>>(x, xb, (int)(NE / 4));
    cvt_w4<<<dim3((int)(WE / 1024), 4), blk, 0, stream>>>(wq, wk, wv, wo, wqb, wkb, wvb, wob);

    gemm_qk_kernel<<<dim3(N_ / 128, M_ / 128, 2), blk, 0, stream>>>(xb, wqb, wkb, qb, kb);
    gemm_v_kernel<<<dim3(N_ / 128, M_ / 128, 1), blk, 0, stream>>>(xb, wvb, vtb);
    rope_qk<<<dim3((B_ * S_ * H_ * 32) / 256), blk, 0, stream>>>(qb, kb, tp);
    attn_kernel<<<dim3((S_ / 128) * H_ * B_), blk, 0, stream>>>(qb, kb, vtb, ob);
    gemm_out_kernel<<<dim3(N_ / 128, M_ / 128, 1), blk, 0, stream>>>(ob, wob, out);
}